// Round 1
// baseline (330.009 us; speedup 1.0000x reference)
//
#include <hip/hip_runtime.h>
#include <math.h>

#define S 64
#define NRES 384
#define CM 256
#define CZ 128
#define NH 8
#define CH 32
#define HC 256

// workspace offsets (in floats)
#define OFF_BIAS 0
#define OFF_A    512
#define OFF_MU   (OFF_A + NH*NRES*NRES)          // 512 + 1,179,648
#define OFF_RS   (OFF_MU + S*NRES)
#define OFF_V    (OFF_RS + S*NRES)
#define OFF_G    (OFF_V + NH*S*NRES*CH)
#define OFF_O    (OFF_G + S*NRES*HC)

// ---------------- kernel 1: mask bias -------------------------------------
__global__ void k_bias(const float* __restrict__ mask, float* __restrict__ bias) {
    int k = threadIdx.x;
    if (k >= NRES) return;
    float mx = -1e30f;
    for (int s = 0; s < S; ++s) mx = fmaxf(mx, mask[s * NRES + k]);
    bias[k] = 1e9f * (mx - 1.0f);
}

// ---------------- kernel 2: LN(z)@Wz + softmax -> a[h][q][k] ---------------
__global__ __launch_bounds__(256) void k_pair(const float* __restrict__ z,
        const float* __restrict__ lw, const float* __restrict__ lb,
        const float* __restrict__ Wz, const float* __restrict__ bias,
        float* __restrict__ a_out) {
    __shared__ float sWzT[NH][CZ];
    __shared__ float sLw[CZ], sLb[CZ];
    __shared__ float sZb[NH][NRES];
    const int tid = threadIdx.x;
    const int q = blockIdx.x;
    if (tid < CZ) { sLw[tid] = lw[tid]; sLb[tid] = lb[tid]; }
    for (int i = tid; i < CZ * NH; i += 256) {
        int c = i >> 3, h = i & 7;
        sWzT[h][c] = Wz[i];
    }
    __syncthreads();
    const int grp = tid >> 5, lane = tid & 31;
    const int c0 = lane * 4;
    for (int kb = 0; kb < NRES / 8; ++kb) {
        const int k = kb * 8 + grp;
        const float4 zz = *(const float4*)&z[((size_t)q * NRES + k) * CZ + c0];
        float sm = zz.x + zz.y + zz.z + zz.w;
        float sq = zz.x*zz.x + zz.y*zz.y + zz.z*zz.z + zz.w*zz.w;
        #pragma unroll
        for (int off = 16; off >= 1; off >>= 1) {
            sm += __shfl_xor(sm, off);
            sq += __shfl_xor(sq, off);
        }
        const float mu = sm * (1.0f / CZ);
        const float var = sq * (1.0f / CZ) - mu * mu;
        const float rs = rsqrtf(var + 1e-5f);
        const float n0 = (zz.x - mu) * rs * sLw[c0+0] + sLb[c0+0];
        const float n1 = (zz.y - mu) * rs * sLw[c0+1] + sLb[c0+1];
        const float n2 = (zz.z - mu) * rs * sLw[c0+2] + sLb[c0+2];
        const float n3 = (zz.w - mu) * rs * sLw[c0+3] + sLb[c0+3];
        float p[NH];
        #pragma unroll
        for (int h = 0; h < NH; ++h) {
            const float4 w4 = *(const float4*)&sWzT[h][c0];
            p[h] = n0*w4.x + n1*w4.y + n2*w4.z + n3*w4.w;
        }
        #pragma unroll
        for (int off = 16; off >= 1; off >>= 1) {
            #pragma unroll
            for (int h = 0; h < NH; ++h) p[h] += __shfl_xor(p[h], off);
        }
        if (lane == 0) {
            const float bk = bias[k];
            #pragma unroll
            for (int h = 0; h < NH; ++h) sZb[h][k] = p[h] + bk;
        }
    }
    __syncthreads();
    const int wave = tid >> 6, wl = tid & 63;
    for (int h = wave; h < NH; h += 4) {
        float v[6];
        float mx = -1e30f;
        #pragma unroll
        for (int t = 0; t < 6; ++t) { v[t] = sZb[h][wl + 64*t]; mx = fmaxf(mx, v[t]); }
        #pragma unroll
        for (int off = 32; off >= 1; off >>= 1) mx = fmaxf(mx, __shfl_xor(mx, off));
        float sum = 0.f;
        #pragma unroll
        for (int t = 0; t < 6; ++t) { v[t] = expf(v[t] - mx); sum += v[t]; }
        #pragma unroll
        for (int off = 32; off >= 1; off >>= 1) sum += __shfl_xor(sum, off);
        const float inv = 1.0f / sum;
        #pragma unroll
        for (int t = 0; t < 6; ++t)
            a_out[((size_t)h * NRES + q) * NRES + wl + 64*t] = v[t] * inv;
    }
}

// ---------------- kernel 3: LN(m) row stats --------------------------------
__global__ __launch_bounds__(256) void k_rowstats(const float* __restrict__ m,
        float* __restrict__ mu_o, float* __restrict__ rs_o) {
    const int row = blockIdx.x * 4 + (threadIdx.x >> 6);
    const int lane = threadIdx.x & 63;
    const float4 x = *(const float4*)&m[(size_t)row * CM + lane * 4];
    float sm = x.x + x.y + x.z + x.w;
    float sq = x.x*x.x + x.y*x.y + x.z*x.z + x.w*x.w;
    #pragma unroll
    for (int off = 32; off >= 1; off >>= 1) {
        sm += __shfl_xor(sm, off);
        sq += __shfl_xor(sq, off);
    }
    if (lane == 0) {
        const float mu = sm * (1.0f / CM);
        const float var = sq * (1.0f / CM) - mu * mu;
        mu_o[row] = mu;
        rs_o[row] = rsqrtf(var + 1e-5f);
    }
}

// ---------------- kernel 4: [LN(m)] @ [Wv | Wg] ----------------------------
// M=24576 K=256 N=512. 64x64 tile, 256 thr, 4x4 micro.
__global__ __launch_bounds__(256) void k_gemm_vg(const float* __restrict__ m,
        const float* __restrict__ mu_, const float* __restrict__ rs_,
        const float* __restrict__ lw, const float* __restrict__ lb,
        const float* __restrict__ Wv, const float* __restrict__ Wg,
        float* __restrict__ v_o, float* __restrict__ g_o) {
    __shared__ float As[16][68];   // A^T tile, padded, rows 272B (16B-mult)
    __shared__ float Bs[16][64];
    __shared__ float sLw[CM], sLb[CM];
    const int tid = threadIdx.x;
    const int m0 = (int)(blockIdx.x >> 3) * 64;
    const int n0 = (int)(blockIdx.x & 7) * 64;
    sLw[tid] = lw[tid]; sLb[tid] = lb[tid];
    const int ar = tid >> 2;          // 0..63 (row within tile)
    const int ak = (tid & 3) * 4;     // 0,4,8,12
    const int br = tid >> 6;          // 0..3
    const int bc = tid & 63;
    const int tx = tid & 15, ty = tid >> 4;
    const int rowA = m0 + ar;
    const float muv = mu_[rowA], rsv = rs_[rowA];
    float acc[4][4] = {};
    for (int kt = 0; kt < CM; kt += 16) {
        __syncthreads();
        {
            const float4 x = *(const float4*)&m[(size_t)rowA * CM + kt + ak];
            As[ak+0][ar] = (x.x - muv) * rsv * sLw[kt+ak+0] + sLb[kt+ak+0];
            As[ak+1][ar] = (x.y - muv) * rsv * sLw[kt+ak+1] + sLb[kt+ak+1];
            As[ak+2][ar] = (x.z - muv) * rsv * sLw[kt+ak+2] + sLb[kt+ak+2];
            As[ak+3][ar] = (x.w - muv) * rsv * sLw[kt+ak+3] + sLb[kt+ak+3];
        }
        #pragma unroll
        for (int i = 0; i < 4; ++i) {
            const int kk = br + i * 4;
            const int j = n0 + bc;
            Bs[kk][bc] = (j < HC) ? Wv[(size_t)(kt + kk) * HC + j]
                                  : Wg[(size_t)(kt + kk) * HC + (j - HC)];
        }
        __syncthreads();
        #pragma unroll
        for (int kk = 0; kk < 16; ++kk) {
            const float4 a4 = *(const float4*)&As[kk][ty * 4];
            const float4 b4 = *(const float4*)&Bs[kk][tx * 4];
            acc[0][0] += a4.x*b4.x; acc[0][1] += a4.x*b4.y; acc[0][2] += a4.x*b4.z; acc[0][3] += a4.x*b4.w;
            acc[1][0] += a4.y*b4.x; acc[1][1] += a4.y*b4.y; acc[1][2] += a4.y*b4.z; acc[1][3] += a4.y*b4.w;
            acc[2][0] += a4.z*b4.x; acc[2][1] += a4.z*b4.y; acc[2][2] += a4.z*b4.z; acc[2][3] += a4.z*b4.w;
            acc[3][0] += a4.w*b4.x; acc[3][1] += a4.w*b4.y; acc[3][2] += a4.w*b4.z; acc[3][3] += a4.w*b4.w;
        }
    }
    #pragma unroll
    for (int i = 0; i < 4; ++i) {
        const int r = m0 + ty * 4 + i;
        const int s = r / NRES, n = r % NRES;
        #pragma unroll
        for (int j = 0; j < 4; ++j) {
            const int col = n0 + tx * 4 + j;
            const float val = acc[i][j];
            if (col < HC) {
                const int h = col >> 5, c = col & 31;
                v_o[(((size_t)h * S + s) * NRES + n) * CH + c] = val;
            } else {
                g_o[(size_t)r * HC + (col - HC)] = 1.0f / (1.0f + expf(-val));
            }
        }
    }
}

// ---------------- kernel 5: o[s,q,h*32+c] = sum_k a[h,q,k] v[h,s,k,c] ------
__global__ __launch_bounds__(256) void k_attn(const float* __restrict__ a_,
        const float* __restrict__ v_, float* __restrict__ o_) {
    __shared__ float As[64][33];
    __shared__ float Bs[32][32];
    const int tid = threadIdx.x;
    const int qt = (int)(blockIdx.x % 6);
    const int hs = (int)(blockIdx.x / 6);
    const int h = hs >> 6, s = hs & 63;
    const int q0 = qt * 64;
    const int tx = tid & 7;           // col group: c = tx*4..tx*4+3
    const int qy = tid >> 3;          // 0..31 : rows qy*2, qy*2+1
    const int ar = tid >> 2;          // A-load row 0..63
    const int ak = (tid & 3) * 8;     // A-load col 0,8,16,24
    const int lc = tid & 31;          // B-load col
    float acc[2][4] = {};
    const float* abase = a_ + ((size_t)h * NRES + q0) * NRES;
    const float* vbase = v_ + (size_t)(h * S + s) * NRES * CH;
    for (int kt = 0; kt < NRES; kt += 32) {
        __syncthreads();
        {
            const float4 x0 = *(const float4*)&abase[(size_t)ar * NRES + kt + ak];
            const float4 x1 = *(const float4*)&abase[(size_t)ar * NRES + kt + ak + 4];
            As[ar][ak+0]=x0.x; As[ar][ak+1]=x0.y; As[ar][ak+2]=x0.z; As[ar][ak+3]=x0.w;
            As[ar][ak+4]=x1.x; As[ar][ak+5]=x1.y; As[ar][ak+6]=x1.z; As[ar][ak+7]=x1.w;
        }
        #pragma unroll
        for (int i = 0; i < 4; ++i) {
            const int kk = (tid >> 5) + i * 8;
            Bs[kk][lc] = vbase[(size_t)(kt + kk) * CH + lc];
        }
        __syncthreads();
        #pragma unroll
        for (int kk = 0; kk < 32; ++kk) {
            const float a0 = As[qy*2+0][kk];
            const float a1 = As[qy*2+1][kk];
            const float4 b4 = *(const float4*)&Bs[kk][tx * 4];
            acc[0][0] += a0*b4.x; acc[0][1] += a0*b4.y; acc[0][2] += a0*b4.z; acc[0][3] += a0*b4.w;
            acc[1][0] += a1*b4.x; acc[1][1] += a1*b4.y; acc[1][2] += a1*b4.z; acc[1][3] += a1*b4.w;
        }
    }
    #pragma unroll
    for (int i = 0; i < 2; ++i) {
        float4 v4 = make_float4(acc[i][0], acc[i][1], acc[i][2], acc[i][3]);
        *(float4*)&o_[((size_t)s * NRES + q0 + qy*2 + i) * HC + h * CH + tx * 4] = v4;
    }
}

// ---------------- kernel 6: out = (o*g) @ Wo --------------------------------
__global__ __launch_bounds__(256) void k_gemm_out(const float* __restrict__ o_,
        const float* __restrict__ g_, const float* __restrict__ Wo,
        float* __restrict__ out) {
    __shared__ float As[16][68];
    __shared__ float Bs[16][64];
    const int tid = threadIdx.x;
    const int m0 = (int)(blockIdx.x >> 2) * 64;
    const int n0 = (int)(blockIdx.x & 3) * 64;
    const int ar = tid >> 2;
    const int ak = (tid & 3) * 4;
    const int br = tid >> 6;
    const int bc = tid & 63;
    const int tx = tid & 15, ty = tid >> 4;
    const int rowA = m0 + ar;
    float acc[4][4] = {};
    for (int kt = 0; kt < HC; kt += 16) {
        __syncthreads();
        {
            const float4 x = *(const float4*)&o_[(size_t)rowA * HC + kt + ak];
            const float4 g4 = *(const float4*)&g_[(size_t)rowA * HC + kt + ak];
            As[ak+0][ar] = x.x * g4.x;
            As[ak+1][ar] = x.y * g4.y;
            As[ak+2][ar] = x.z * g4.z;
            As[ak+3][ar] = x.w * g4.w;
        }
        #pragma unroll
        for (int i = 0; i < 4; ++i) {
            const int kk = br + i * 4;
            Bs[kk][bc] = Wo[(size_t)(kt + kk) * CM + n0 + bc];
        }
        __syncthreads();
        #pragma unroll
        for (int kk = 0; kk < 16; ++kk) {
            const float4 a4 = *(const float4*)&As[kk][ty * 4];
            const float4 b4 = *(const float4*)&Bs[kk][tx * 4];
            acc[0][0] += a4.x*b4.x; acc[0][1] += a4.x*b4.y; acc[0][2] += a4.x*b4.z; acc[0][3] += a4.x*b4.w;
            acc[1][0] += a4.y*b4.x; acc[1][1] += a4.y*b4.y; acc[1][2] += a4.y*b4.z; acc[1][3] += a4.y*b4.w;
            acc[2][0] += a4.z*b4.x; acc[2][1] += a4.z*b4.y; acc[2][2] += a4.z*b4.z; acc[2][3] += a4.z*b4.w;
            acc[3][0] += a4.w*b4.x; acc[3][1] += a4.w*b4.y; acc[3][2] += a4.w*b4.z; acc[3][3] += a4.w*b4.w;
        }
    }
    #pragma unroll
    for (int i = 0; i < 4; ++i) {
        const int r = m0 + ty * 4 + i;
        #pragma unroll
        for (int j = 0; j < 4; ++j) {
            out[(size_t)r * CM + n0 + tx * 4 + j] = acc[i][j];
        }
    }
}

extern "C" void kernel_launch(void* const* d_in, const int* in_sizes, int n_in,
                              void* d_out, int out_size, void* d_ws, size_t ws_size,
                              hipStream_t stream) {
    const float* m      = (const float*)d_in[0];
    const float* z      = (const float*)d_in[1];
    const float* mask   = (const float*)d_in[2];
    const float* ln_m_w = (const float*)d_in[3];
    const float* ln_m_b = (const float*)d_in[4];
    const float* ln_z_w = (const float*)d_in[5];
    const float* ln_z_b = (const float*)d_in[6];
    const float* Wz     = (const float*)d_in[7];
    const float* Wv     = (const float*)d_in[8];
    const float* Wg     = (const float*)d_in[9];
    const float* Wo     = (const float*)d_in[10];
    float* out = (float*)d_out;
    float* ws  = (float*)d_ws;

    float* bias = ws + OFF_BIAS;
    float* a    = ws + OFF_A;
    float* muw  = ws + OFF_MU;
    float* rsw  = ws + OFF_RS;
    float* vw   = ws + OFF_V;
    float* gw   = ws + OFF_G;
    float* ow   = ws + OFF_O;

    k_bias<<<1, NRES, 0, stream>>>(mask, bias);
    k_pair<<<NRES, 256, 0, stream>>>(z, ln_z_w, ln_z_b, Wz, bias, a);
    k_rowstats<<<(S * NRES) / 4, 256, 0, stream>>>(m, muw, rsw);
    k_gemm_vg<<<384 * 8, 256, 0, stream>>>(m, muw, rsw, ln_m_w, ln_m_b, Wv, Wg, vw, gw);
    k_attn<<<512 * 6, 256, 0, stream>>>(a, vw, ow);
    k_gemm_out<<<384 * 4, 256, 0, stream>>>(ow, gw, Wo, out);
}

// Round 2
// 163.752 us; speedup vs baseline: 2.0153x; 2.0153x over previous
//
#include <hip/hip_runtime.h>
#include <math.h>

#define S 64
#define NRES 384
#define CM 256
#define CZ 128
#define NH 8
#define CH 32
#define HC 256

typedef unsigned short u16;
typedef __attribute__((ext_vector_type(8))) short bf16x8;
typedef __attribute__((ext_vector_type(4))) float f32x4;
typedef __attribute__((ext_vector_type(8))) unsigned short ushort8;
typedef __attribute__((ext_vector_type(4))) unsigned short ushort4_t;

// ---- workspace byte offsets ----
#define OFF_BIAS 0            // 384 f32
#define OFF_MU   4096         // 24576 f32
#define OFF_RS   102400       // 24576 f32
#define OFF_WT   200704       // 512*256 bf16 (Wv|Wg transposed)
#define OFF_WOT  462848       // 256*256 bf16 (Wo transposed)
#define OFF_A    593920       // 8*384*384 bf16
#define OFF_VT   2953216      // [h][s][c][n] 8*64*32*384 bf16
#define OFF_G    15536128     // 24576*256 bf16
#define OFF_O    28119040     // 24576*256 bf16

__device__ __forceinline__ u16 f2bf(float f) {
    union { float f; unsigned int u; } v; v.f = f;
    unsigned int u = v.u;
    u += 0x7fff + ((u >> 16) & 1);
    return (u16)(u >> 16);
}
__device__ __forceinline__ float bf2f(u16 b) {
    union { float f; unsigned int u; } v; v.u = ((unsigned int)b) << 16;
    return v.f;
}

// ---------------- mask bias -------------------------------------------------
__global__ void k_bias(const float* __restrict__ mask, float* __restrict__ bias) {
    int k = threadIdx.x;
    if (k >= NRES) return;
    float mx = -1e30f;
    for (int s = 0; s < S; ++s) mx = fmaxf(mx, mask[s * NRES + k]);
    bias[k] = 1e9f * (mx - 1.0f);
}

// ---------------- weight prep: transpose + bf16 -----------------------------
__global__ __launch_bounds__(256) void k_prep_vg(const float* __restrict__ Wv,
        const float* __restrict__ Wg, u16* __restrict__ Wt) {
    const int i = blockIdx.x * 256 + threadIdx.x;   // 131072
    const int n = i >> 8, k = i & 255;
    const float v = (n < HC) ? Wv[(size_t)k * HC + n] : Wg[(size_t)k * HC + (n - HC)];
    Wt[i] = f2bf(v);
}
__global__ __launch_bounds__(256) void k_prep_o(const float* __restrict__ Wo,
        u16* __restrict__ Wot) {
    const int i = blockIdx.x * 256 + threadIdx.x;   // 65536
    const int n = i >> 8, k = i & 255;
    Wot[i] = f2bf(Wo[(size_t)k * CM + n]);
}

// ---------------- LN(z)@Wz + softmax -> a[h][q][k] (bf16) -------------------
__global__ __launch_bounds__(256) void k_pair(const float* __restrict__ z,
        const float* __restrict__ lw, const float* __restrict__ lb,
        const float* __restrict__ Wz, const float* __restrict__ bias,
        u16* __restrict__ a_out) {
    __shared__ float sWzT[NH][CZ];
    __shared__ float sLw[CZ], sLb[CZ];
    __shared__ float sZb[NH][NRES];
    const int tid = threadIdx.x;
    const int q = blockIdx.x;
    if (tid < CZ) { sLw[tid] = lw[tid]; sLb[tid] = lb[tid]; }
    for (int i = tid; i < CZ * NH; i += 256) {
        int c = i >> 3, h = i & 7;
        sWzT[h][c] = Wz[i];
    }
    __syncthreads();
    const int grp = tid >> 5, lane = tid & 31;
    const int c0 = lane * 4;
    for (int kb = 0; kb < NRES / 8; ++kb) {
        const int k = kb * 8 + grp;
        const float4 zz = *(const float4*)&z[((size_t)q * NRES + k) * CZ + c0];
        float sm = zz.x + zz.y + zz.z + zz.w;
        float sq = zz.x*zz.x + zz.y*zz.y + zz.z*zz.z + zz.w*zz.w;
        #pragma unroll
        for (int off = 16; off >= 1; off >>= 1) {
            sm += __shfl_xor(sm, off);
            sq += __shfl_xor(sq, off);
        }
        const float mu = sm * (1.0f / CZ);
        const float var = sq * (1.0f / CZ) - mu * mu;
        const float rs = rsqrtf(var + 1e-5f);
        const float n0 = (zz.x - mu) * rs * sLw[c0+0] + sLb[c0+0];
        const float n1 = (zz.y - mu) * rs * sLw[c0+1] + sLb[c0+1];
        const float n2 = (zz.z - mu) * rs * sLw[c0+2] + sLb[c0+2];
        const float n3 = (zz.w - mu) * rs * sLw[c0+3] + sLb[c0+3];
        float p[NH];
        #pragma unroll
        for (int h = 0; h < NH; ++h) {
            const float4 w4 = *(const float4*)&sWzT[h][c0];
            p[h] = n0*w4.x + n1*w4.y + n2*w4.z + n3*w4.w;
        }
        #pragma unroll
        for (int off = 16; off >= 1; off >>= 1) {
            #pragma unroll
            for (int h = 0; h < NH; ++h) p[h] += __shfl_xor(p[h], off);
        }
        if (lane == 0) {
            const float bk = bias[k];
            #pragma unroll
            for (int h = 0; h < NH; ++h) sZb[h][k] = p[h] + bk;
        }
    }
    __syncthreads();
    const int wave = tid >> 6, wl = tid & 63;
    for (int h = wave; h < NH; h += 4) {
        float v[6];
        float mx = -1e30f;
        #pragma unroll
        for (int t = 0; t < 6; ++t) { v[t] = sZb[h][wl + 64*t]; mx = fmaxf(mx, v[t]); }
        #pragma unroll
        for (int off = 32; off >= 1; off >>= 1) mx = fmaxf(mx, __shfl_xor(mx, off));
        float sum = 0.f;
        #pragma unroll
        for (int t = 0; t < 6; ++t) { v[t] = expf(v[t] - mx); sum += v[t]; }
        #pragma unroll
        for (int off = 32; off >= 1; off >>= 1) sum += __shfl_xor(sum, off);
        const float inv = 1.0f / sum;
        #pragma unroll
        for (int t = 0; t < 6; ++t)
            a_out[((size_t)h * NRES + q) * NRES + wl + 64*t] = f2bf(v[t] * inv);
    }
}

// ---------------- LN(m) row stats ------------------------------------------
__global__ __launch_bounds__(256) void k_rowstats(const float* __restrict__ m,
        float* __restrict__ mu_o, float* __restrict__ rs_o) {
    const int row = blockIdx.x * 4 + (threadIdx.x >> 6);
    const int lane = threadIdx.x & 63;
    const float4 x = *(const float4*)&m[(size_t)row * CM + lane * 4];
    float sm = x.x + x.y + x.z + x.w;
    float sq = x.x*x.x + x.y*x.y + x.z*x.z + x.w*x.w;
    #pragma unroll
    for (int off = 32; off >= 1; off >>= 1) {
        sm += __shfl_xor(sm, off);
        sq += __shfl_xor(sq, off);
    }
    if (lane == 0) {
        const float mu = sm * (1.0f / CM);
        const float var = sq * (1.0f / CM) - mu * mu;
        mu_o[row] = mu;
        rs_o[row] = rsqrtf(var + 1e-5f);
    }
}

// ---------------- MFMA GEMM: [LN(m)]@[Wv|Wg] -> vt (transposed) + g ---------
// M=24576 K=256 N=512. 128x128 tile, 4 waves, each wave 64x64 (4x4 frags).
__global__ __launch_bounds__(256) void k_gemm_vg(const float* __restrict__ m,
        const float* __restrict__ mu_, const float* __restrict__ rs_,
        const float* __restrict__ lw, const float* __restrict__ lb,
        const u16* __restrict__ Wt, u16* __restrict__ vt, u16* __restrict__ g_) {
    __shared__ u16 As[128][40];
    __shared__ u16 Bs[128][40];
    __shared__ float sLw[CM], sLb[CM];
    const int tid = threadIdx.x;
    const int mt = blockIdx.x >> 2, nt = blockIdx.x & 3;
    const int m0 = mt * 128, n0 = nt * 128;
    sLw[tid] = lw[tid]; sLb[tid] = lb[tid];
    const int wave = tid >> 6, lane = tid & 63;
    const int wm = (wave >> 1) * 64, wn = (wave & 1) * 64;
    const int rl = lane & 15, kg = lane >> 4;
    const int sr = tid >> 1, sh = (tid & 1) * 16;
    const float* mrow = m + (size_t)(m0 + sr) * CM;
    const float muv = mu_[m0 + sr], rsv = rs_[m0 + sr];
    const u16* wrow = Wt + (size_t)(n0 + sr) * CM;
    f32x4 acc[4][4] = {};
    __syncthreads();
    for (int kt = 0; kt < CM; kt += 32) {
        if (kt) __syncthreads();
        {
            u16 tmp[16];
            #pragma unroll
            for (int p = 0; p < 4; ++p) {
                const float4 x = *(const float4*)&mrow[kt + sh + p*4];
                const int kb = kt + sh + p*4;
                tmp[p*4+0] = f2bf((x.x - muv) * rsv * sLw[kb+0] + sLb[kb+0]);
                tmp[p*4+1] = f2bf((x.y - muv) * rsv * sLw[kb+1] + sLb[kb+1]);
                tmp[p*4+2] = f2bf((x.z - muv) * rsv * sLw[kb+2] + sLb[kb+2]);
                tmp[p*4+3] = f2bf((x.w - muv) * rsv * sLw[kb+3] + sLb[kb+3]);
            }
            *(ushort8*)&As[sr][sh]     = *(ushort8*)&tmp[0];
            *(ushort8*)&As[sr][sh + 8] = *(ushort8*)&tmp[8];
            *(ushort8*)&Bs[sr][sh]     = *(const ushort8*)&wrow[kt + sh];
            *(ushort8*)&Bs[sr][sh + 8] = *(const ushort8*)&wrow[kt + sh + 8];
        }
        __syncthreads();
        bf16x8 af[4], bfr[4];
        #pragma unroll
        for (int i = 0; i < 4; ++i) af[i]  = *(const bf16x8*)&As[wm + i*16 + rl][kg*8];
        #pragma unroll
        for (int j = 0; j < 4; ++j) bfr[j] = *(const bf16x8*)&Bs[wn + j*16 + rl][kg*8];
        #pragma unroll
        for (int i = 0; i < 4; ++i)
            #pragma unroll
            for (int j = 0; j < 4; ++j)
                acc[i][j] = __builtin_amdgcn_mfma_f32_16x16x32_bf16(af[i], bfr[j], acc[i][j], 0, 0, 0);
    }
    if (n0 < HC) {
        #pragma unroll
        for (int i = 0; i < 4; ++i) {
            #pragma unroll
            for (int r = 0; r < 4; ++r) {
                const int row = m0 + wm + i*16 + kg*4 + r;
                const int s = row / NRES, n = row - s * NRES;
                #pragma unroll
                for (int j = 0; j < 4; ++j) {
                    const int col = n0 + wn + j*16 + rl;
                    const int h = col >> 5, c = col & 31;
                    vt[(((size_t)h * S + s) * CH + c) * NRES + n] = f2bf(acc[i][j][r]);
                }
            }
        }
    } else {
        #pragma unroll
        for (int i = 0; i < 4; ++i) {
            #pragma unroll
            for (int r = 0; r < 4; ++r) {
                const int row = m0 + wm + i*16 + kg*4 + r;
                #pragma unroll
                for (int j = 0; j < 4; ++j) {
                    const int gc = n0 + wn + j*16 + rl - HC;
                    const float val = acc[i][j][r];
                    g_[(size_t)row * HC + gc] = f2bf(1.0f / (1.0f + expf(-val)));
                }
            }
        }
    }
}

// ---------------- MFMA einsum: o^T[c][q] = sum_k vt[h][s][c][k]*a[h][q][k] --
// block = (h, s, q-half of 192). 4 waves, each 48 q (3 q-frags) x 32 c (2).
__global__ __launch_bounds__(256) void k_attn(const u16* __restrict__ a_,
        const u16* __restrict__ vt, u16* __restrict__ o_) {
    __shared__ u16 Vs[32][392];
    __shared__ u16 Qs[192][40];
    const int tid = threadIdx.x;
    const int b = blockIdx.x;
    const int qh = b & 1, s = (b >> 1) & 63, h = b >> 7;
    const int q0 = qh * 192;
    const int wave = tid >> 6, lane = tid & 63;
    const int rl = lane & 15, kg = lane >> 4;
    const u16* vbase = vt + ((size_t)(h * S + s) * CH) * NRES;
    #pragma unroll
    for (int t = 0; t < 6; ++t) {
        const int idx = tid + t * 256;            // 1536 chunks of 8
        const int c = idx / 48, kk = (idx % 48) * 8;
        *(ushort8*)&Vs[c][kk] = *(const ushort8*)&vbase[c * NRES + kk];
    }
    const u16* abase = a_ + (size_t)h * NRES * NRES + (size_t)q0 * NRES;
    const int qw = wave * 48;
    f32x4 acc[2][3] = {};
    for (int kt = 0; kt < NRES; kt += 32) {
        __syncthreads();
        #pragma unroll
        for (int t = 0; t < 3; ++t) {
            const int ci = tid + t * 256;         // 768 chunks of 8
            const int q = ci >> 2, kp = (ci & 3) * 8;
            *(ushort8*)&Qs[q][kp] = *(const ushort8*)&abase[(size_t)q * NRES + kt + kp];
        }
        __syncthreads();
        bf16x8 vf[2], qf[3];
        #pragma unroll
        for (int i = 0; i < 2; ++i) vf[i] = *(const bf16x8*)&Vs[i*16 + rl][kt + kg*8];
        #pragma unroll
        for (int j = 0; j < 3; ++j) qf[j] = *(const bf16x8*)&Qs[qw + j*16 + rl][kg*8];
        #pragma unroll
        for (int i = 0; i < 2; ++i)
            #pragma unroll
            for (int j = 0; j < 3; ++j)
                acc[i][j] = __builtin_amdgcn_mfma_f32_16x16x32_bf16(vf[i], qf[j], acc[i][j], 0, 0, 0);
    }
    #pragma unroll
    for (int i = 0; i < 2; ++i)
        #pragma unroll
        for (int j = 0; j < 3; ++j) {
            const int q = q0 + qw + j*16 + rl;
            const int c0 = i*16 + kg*4;
            u16 tmp[4];
            #pragma unroll
            for (int r = 0; r < 4; ++r) tmp[r] = f2bf(acc[i][j][r]);
            *(ushort4_t*)&o_[((size_t)s * NRES + q) * HC + h * CH + c0] = *(ushort4_t*)tmp;
        }
}

// ---------------- MFMA GEMM: out = (o*g) @ Wo -------------------------------
__global__ __launch_bounds__(256) void k_gemm_out(const u16* __restrict__ o_,
        const u16* __restrict__ g_, const u16* __restrict__ Wot,
        float* __restrict__ out) {
    __shared__ u16 As[128][40];
    __shared__ u16 Bs[128][40];
    const int tid = threadIdx.x;
    const int mt = blockIdx.x >> 1, nt = blockIdx.x & 1;
    const int m0 = mt * 128, n0 = nt * 128;
    const int wave = tid >> 6, lane = tid & 63;
    const int wm = (wave >> 1) * 64, wn = (wave & 1) * 64;
    const int rl = lane & 15, kg = lane >> 4;
    const int sr = tid >> 1, sh = (tid & 1) * 16;
    const u16* orow = o_ + (size_t)(m0 + sr) * HC;
    const u16* grow = g_ + (size_t)(m0 + sr) * HC;
    const u16* wrow = Wot + (size_t)(n0 + sr) * HC;
    f32x4 acc[4][4] = {};
    for (int kt = 0; kt < HC; kt += 32) {
        if (kt) __syncthreads();
        {
            u16 tmp[16];
            const ushort8 ov0 = *(const ushort8*)&orow[kt + sh];
            const ushort8 ov1 = *(const ushort8*)&orow[kt + sh + 8];
            const ushort8 gv0 = *(const ushort8*)&grow[kt + sh];
            const ushort8 gv1 = *(const ushort8*)&grow[kt + sh + 8];
            #pragma unroll
            for (int p = 0; p < 8; ++p) {
                tmp[p]     = f2bf(bf2f(ov0[p]) * bf2f(gv0[p]));
                tmp[p + 8] = f2bf(bf2f(ov1[p]) * bf2f(gv1[p]));
            }
            *(ushort8*)&As[sr][sh]     = *(ushort8*)&tmp[0];
            *(ushort8*)&As[sr][sh + 8] = *(ushort8*)&tmp[8];
            *(ushort8*)&Bs[sr][sh]     = *(const ushort8*)&wrow[kt + sh];
            *(ushort8*)&Bs[sr][sh + 8] = *(const ushort8*)&wrow[kt + sh + 8];
        }
        __syncthreads();
        bf16x8 af[4], bfr[4];
        #pragma unroll
        for (int i = 0; i < 4; ++i) af[i]  = *(const bf16x8*)&As[wm + i*16 + rl][kg*8];
        #pragma unroll
        for (int j = 0; j < 4; ++j) bfr[j] = *(const bf16x8*)&Bs[wn + j*16 + rl][kg*8];
        #pragma unroll
        for (int i = 0; i < 4; ++i)
            #pragma unroll
            for (int j = 0; j < 4; ++j)
                acc[i][j] = __builtin_amdgcn_mfma_f32_16x16x32_bf16(af[i], bfr[j], acc[i][j], 0, 0, 0);
    }
    #pragma unroll
    for (int i = 0; i < 4; ++i)
        #pragma unroll
        for (int r = 0; r < 4; ++r) {
            const int row = m0 + wm + i*16 + kg*4 + r;
            #pragma unroll
            for (int j = 0; j < 4; ++j)
                out[(size_t)row * CM + n0 + wn + j*16 + rl] = acc[i][j][r];
        }
}

extern "C" void kernel_launch(void* const* d_in, const int* in_sizes, int n_in,
                              void* d_out, int out_size, void* d_ws, size_t ws_size,
                              hipStream_t stream) {
    const float* m      = (const float*)d_in[0];
    const float* z      = (const float*)d_in[1];
    const float* mask   = (const float*)d_in[2];
    const float* ln_m_w = (const float*)d_in[3];
    const float* ln_m_b = (const float*)d_in[4];
    const float* ln_z_w = (const float*)d_in[5];
    const float* ln_z_b = (const float*)d_in[6];
    const float* Wz     = (const float*)d_in[7];
    const float* Wv     = (const float*)d_in[8];
    const float* Wg     = (const float*)d_in[9];
    const float* Wo     = (const float*)d_in[10];
    float* out = (float*)d_out;
    char* ws = (char*)d_ws;

    float* bias = (float*)(ws + OFF_BIAS);
    float* muw  = (float*)(ws + OFF_MU);
    float* rsw  = (float*)(ws + OFF_RS);
    u16* Wt     = (u16*)(ws + OFF_WT);
    u16* Wot    = (u16*)(ws + OFF_WOT);
    u16* a      = (u16*)(ws + OFF_A);
    u16* vtw    = (u16*)(ws + OFF_VT);
    u16* gw     = (u16*)(ws + OFF_G);
    u16* ow     = (u16*)(ws + OFF_O);

    k_bias<<<1, NRES, 0, stream>>>(mask, bias);
    k_prep_vg<<<512, 256, 0, stream>>>(Wv, Wg, Wt);
    k_prep_o<<<256, 256, 0, stream>>>(Wo, Wot);
    k_rowstats<<<(S * NRES) / 4, 256, 0, stream>>>(m, muw, rsw);
    k_pair<<<NRES, 256, 0, stream>>>(z, ln_z_w, ln_z_b, Wz, bias, a);
    k_gemm_vg<<<192 * 4, 256, 0, stream>>>(m, muw, rsw, ln_m_w, ln_m_b, Wt, vtw, gw);
    k_attn<<<NH * S * 2, 256, 0, stream>>>(a, vtw, ow);
    k_gemm_out<<<192 * 2, 256, 0, stream>>>(ow, gw, Wot, out);
}

// Round 3
// 121.422 us; speedup vs baseline: 2.7179x; 1.3486x over previous
//
#include <hip/hip_runtime.h>
#include <math.h>

#define S 64
#define NRES 384
#define CM 256
#define CZ 128
#define NH 8
#define CH 32
#define HC 256

typedef unsigned short u16;
typedef __attribute__((ext_vector_type(8))) short bf16x8;
typedef __attribute__((ext_vector_type(4))) float f32x4;
typedef __attribute__((ext_vector_type(8))) unsigned short ushort8;
typedef __attribute__((ext_vector_type(4))) unsigned short ushort4_t;

// ---- workspace byte offsets ----
#define OFF_BIAS 0            // 384 f32
#define OFF_MU   4096         // 24576 f32
#define OFF_RS   102400       // 24576 f32
#define OFF_WT   200704       // 512*256 bf16 (Wv|Wg transposed)
#define OFF_WOT  462848       // 256*256 bf16 (Wo transposed)
#define OFF_A    593920       // 8*384*384 bf16
#define OFF_VT   2953216      // [h][s][c][n] 8*64*32*384 bf16
#define OFF_G    15536128     // 24576*256 bf16
#define OFF_O    28119040     // 24576*256 bf16 (12.58 MB)
// overlapped (lifetimes disjoint in stream order):
#define OFF_ZB   OFF_O        // 147456*8 f32 = 4.72 MB; dead before k_attn writes o
#define OFF_WWT  OFF_VT       // 16*128 bf16 = 4 KB; dead before k_gemm_vg writes vt
#define OFF_C1   (OFF_VT + 4096)
#define OFF_C2   (OFF_VT + 4160)

__device__ __forceinline__ u16 f2bf(float f) {
    union { float f; unsigned int u; } v; v.f = f;
    unsigned int u = v.u;
    u += 0x7fff + ((u >> 16) & 1);
    return (u16)(u >> 16);
}
__device__ __forceinline__ float bf2f(u16 b) {
    union { float f; unsigned int u; } v; v.u = ((unsigned int)b) << 16;
    return v.f;
}

// ---------------- mask bias -------------------------------------------------
__global__ void k_bias(const float* __restrict__ mask, float* __restrict__ bias) {
    int k = threadIdx.x;
    if (k >= NRES) return;
    float mx = -1e30f;
    for (int s = 0; s < S; ++s) mx = fmaxf(mx, mask[s * NRES + k]);
    bias[k] = 1e9f * (mx - 1.0f);
}

// ---------------- pair-bias prep: WW^T, C1, C2 ------------------------------
__global__ void k_prep_z(const float* __restrict__ Wz, const float* __restrict__ lw,
        const float* __restrict__ lb, u16* __restrict__ WWT,
        float* __restrict__ C1, float* __restrict__ C2) {
    __shared__ float sW[CZ][NH], sB[CZ][NH];
    const int c = threadIdx.x;   // 128 threads
    #pragma unroll
    for (int h = 0; h < NH; ++h) {
        const float wz = Wz[c * NH + h];
        const float ww = lw[c] * wz;
        sW[c][h] = ww;
        sB[c][h] = lb[c] * wz;
        WWT[h * CZ + c] = f2bf(ww);
        WWT[(NH + h) * CZ + c] = 0;   // zero pad rows 8..15
    }
    __syncthreads();
    if (c < NH) {
        float s1 = 0.f, s2 = 0.f;
        for (int k = 0; k < CZ; ++k) { s1 += sW[k][c]; s2 += sB[k][c]; }
        C1[c] = s1; C2[c] = s2;
    } else if (c < 16) {
        C1[c] = 0.f; C2[c] = 0.f;
    }
}

// ---------------- zb logits via MFMA: zb[row][h] ----------------------------
// row = q*384+k (147456 rows). One wave per 16 rows, block=4 waves=64 rows.
__global__ __launch_bounds__(256) void k_zb(const float* __restrict__ z,
        const u16* __restrict__ WWT, const float* __restrict__ C1,
        const float* __restrict__ C2, float* __restrict__ zb) {
    __shared__ float sMu[4][16], sRs[4][16];
    const int tid = threadIdx.x, wave = tid >> 6, lane = tid & 63;
    const int rl = lane & 15, kg = lane >> 4;
    const int row0 = blockIdx.x * 64 + wave * 16;
    const float* zrow = z + (size_t)(row0 + rl) * CZ + kg * 8;
    bf16x8 af[4];
    float sm = 0.f, sq = 0.f;
    #pragma unroll
    for (int t = 0; t < 4; ++t) {
        const float4 x0 = *(const float4*)&zrow[t * 32];
        const float4 x1 = *(const float4*)&zrow[t * 32 + 4];
        float xs[8] = {x0.x, x0.y, x0.z, x0.w, x1.x, x1.y, x1.z, x1.w};
        u16 tmp[8];
        #pragma unroll
        for (int e = 0; e < 8; ++e) {
            sm += xs[e]; sq += xs[e] * xs[e];
            tmp[e] = f2bf(xs[e]);
        }
        af[t] = *(bf16x8*)tmp;
    }
    sm += __shfl_xor(sm, 16); sq += __shfl_xor(sq, 16);
    sm += __shfl_xor(sm, 32); sq += __shfl_xor(sq, 32);
    const float mu = sm * (1.0f / CZ);
    const float var = sq * (1.0f / CZ) - mu * mu;
    const float rs = rsqrtf(var + 1e-5f);
    if (lane < 16) { sMu[wave][lane] = mu; sRs[wave][lane] = rs; }
    const u16* wbase = WWT + rl * CZ + kg * 8;
    bf16x8 bfr[4];
    #pragma unroll
    for (int t = 0; t < 4; ++t) bfr[t] = *(const bf16x8*)&wbase[t * 32];
    f32x4 acc = {};
    #pragma unroll
    for (int t = 0; t < 4; ++t)
        acc = __builtin_amdgcn_mfma_f32_16x16x32_bf16(af[t], bfr[t], acc, 0, 0, 0);
    const float c1 = C1[rl], c2 = C2[rl];
    #pragma unroll
    for (int r = 0; r < 4; ++r) {
        const int rr = kg * 4 + r;
        const float p = sRs[wave][rr] * (acc[r] - sMu[wave][rr] * c1) + c2;
        if (rl < 8) zb[(size_t)(row0 + rr) * NH + rl] = p;
    }
}

// ---------------- softmax over k: a[h][q][k] bf16 ---------------------------
__global__ __launch_bounds__(256) void k_soft(const float* __restrict__ zb,
        const float* __restrict__ bias, u16* __restrict__ a_out) {
    const int w = blockIdx.x * 4 + (threadIdx.x >> 6);
    const int lane = threadIdx.x & 63;
    const int h = w & 7, q = w >> 3;
    float v[6];
    float mx = -1e30f;
    #pragma unroll
    for (int t = 0; t < 6; ++t) {
        const int k = lane + 64 * t;
        v[t] = zb[((size_t)q * NRES + k) * NH + h] + bias[k];
        mx = fmaxf(mx, v[t]);
    }
    #pragma unroll
    for (int off = 32; off >= 1; off >>= 1) mx = fmaxf(mx, __shfl_xor(mx, off));
    float sum = 0.f;
    #pragma unroll
    for (int t = 0; t < 6; ++t) { v[t] = expf(v[t] - mx); sum += v[t]; }
    #pragma unroll
    for (int off = 32; off >= 1; off >>= 1) sum += __shfl_xor(sum, off);
    const float inv = 1.0f / sum;
    #pragma unroll
    for (int t = 0; t < 6; ++t)
        a_out[((size_t)h * NRES + q) * NRES + lane + 64 * t] = f2bf(v[t] * inv);
}

// ---------------- weight prep: transpose + bf16 -----------------------------
__global__ __launch_bounds__(256) void k_prep_vg(const float* __restrict__ Wv,
        const float* __restrict__ Wg, u16* __restrict__ Wt) {
    const int i = blockIdx.x * 256 + threadIdx.x;   // 131072
    const int n = i >> 8, k = i & 255;
    const float v = (n < HC) ? Wv[(size_t)k * HC + n] : Wg[(size_t)k * HC + (n - HC)];
    Wt[i] = f2bf(v);
}
__global__ __launch_bounds__(256) void k_prep_o(const float* __restrict__ Wo,
        u16* __restrict__ Wot) {
    const int i = blockIdx.x * 256 + threadIdx.x;   // 65536
    const int n = i >> 8, k = i & 255;
    Wot[i] = f2bf(Wo[(size_t)k * CM + n]);
}

// ---------------- LN(m) row stats ------------------------------------------
__global__ __launch_bounds__(256) void k_rowstats(const float* __restrict__ m,
        float* __restrict__ mu_o, float* __restrict__ rs_o) {
    const int row = blockIdx.x * 4 + (threadIdx.x >> 6);
    const int lane = threadIdx.x & 63;
    const float4 x = *(const float4*)&m[(size_t)row * CM + lane * 4];
    float sm = x.x + x.y + x.z + x.w;
    float sq = x.x*x.x + x.y*x.y + x.z*x.z + x.w*x.w;
    #pragma unroll
    for (int off = 32; off >= 1; off >>= 1) {
        sm += __shfl_xor(sm, off);
        sq += __shfl_xor(sq, off);
    }
    if (lane == 0) {
        const float mu = sm * (1.0f / CM);
        const float var = sq * (1.0f / CM) - mu * mu;
        mu_o[row] = mu;
        rs_o[row] = rsqrtf(var + 1e-5f);
    }
}

// ---------------- MFMA GEMM: [LN(m)]@[Wv|Wg] -> vt (transposed) + g ---------
__global__ __launch_bounds__(256) void k_gemm_vg(const float* __restrict__ m,
        const float* __restrict__ mu_, const float* __restrict__ rs_,
        const float* __restrict__ lw, const float* __restrict__ lb,
        const u16* __restrict__ Wt, u16* __restrict__ vt, u16* __restrict__ g_) {
    __shared__ u16 As[128][40];
    __shared__ u16 Bs[128][40];
    __shared__ float sLw[CM], sLb[CM];
    const int tid = threadIdx.x;
    const int mt = blockIdx.x >> 2, nt = blockIdx.x & 3;
    const int m0 = mt * 128, n0 = nt * 128;
    sLw[tid] = lw[tid]; sLb[tid] = lb[tid];
    const int wave = tid >> 6, lane = tid & 63;
    const int wm = (wave >> 1) * 64, wn = (wave & 1) * 64;
    const int rl = lane & 15, kg = lane >> 4;
    const int sr = tid >> 1, sh = (tid & 1) * 16;
    const float* mrow = m + (size_t)(m0 + sr) * CM;
    const float muv = mu_[m0 + sr], rsv = rs_[m0 + sr];
    const u16* wrow = Wt + (size_t)(n0 + sr) * CM;
    const bool vhalf = (n0 < HC);
    f32x4 acc[4][4] = {};
    __syncthreads();
    for (int kt = 0; kt < CM; kt += 32) {
        if (kt) __syncthreads();
        {
            u16 tmp[16];
            #pragma unroll
            for (int p = 0; p < 4; ++p) {
                const float4 x = *(const float4*)&mrow[kt + sh + p*4];
                const int kb = kt + sh + p*4;
                tmp[p*4+0] = f2bf((x.x - muv) * rsv * sLw[kb+0] + sLb[kb+0]);
                tmp[p*4+1] = f2bf((x.y - muv) * rsv * sLw[kb+1] + sLb[kb+1]);
                tmp[p*4+2] = f2bf((x.z - muv) * rsv * sLw[kb+2] + sLb[kb+2]);
                tmp[p*4+3] = f2bf((x.w - muv) * rsv * sLw[kb+3] + sLb[kb+3]);
            }
            *(ushort8*)&As[sr][sh]     = *(ushort8*)&tmp[0];
            *(ushort8*)&As[sr][sh + 8] = *(ushort8*)&tmp[8];
            *(ushort8*)&Bs[sr][sh]     = *(const ushort8*)&wrow[kt + sh];
            *(ushort8*)&Bs[sr][sh + 8] = *(const ushort8*)&wrow[kt + sh + 8];
        }
        __syncthreads();
        bf16x8 af[4], bfr[4];
        #pragma unroll
        for (int i = 0; i < 4; ++i) af[i]  = *(const bf16x8*)&As[wm + i*16 + rl][kg*8];
        #pragma unroll
        for (int j = 0; j < 4; ++j) bfr[j] = *(const bf16x8*)&Bs[wn + j*16 + rl][kg*8];
        if (vhalf) {
            #pragma unroll
            for (int j = 0; j < 4; ++j)
                #pragma unroll
                for (int i = 0; i < 4; ++i)
                    acc[j][i] = __builtin_amdgcn_mfma_f32_16x16x32_bf16(bfr[j], af[i], acc[j][i], 0, 0, 0);
        } else {
            #pragma unroll
            for (int i = 0; i < 4; ++i)
                #pragma unroll
                for (int j = 0; j < 4; ++j)
                    acc[i][j] = __builtin_amdgcn_mfma_f32_16x16x32_bf16(af[i], bfr[j], acc[i][j], 0, 0, 0);
        }
    }
    if (vhalf) {
        // D[x=(kg*4+r) -> n-col][y=rl -> m-row]: stores contiguous in n (m-row)
        #pragma unroll
        for (int j = 0; j < 4; ++j)
            #pragma unroll
            for (int r = 0; r < 4; ++r) {
                const int vcol = n0 + wn + j*16 + kg*4 + r;
                const int h = vcol >> 5, c = vcol & 31;
                #pragma unroll
                for (int i = 0; i < 4; ++i) {
                    const int mrowb = m0 + wm + i*16;
                    const int s = mrowb / NRES;
                    const int nn = mrowb - s * NRES + rl;
                    vt[(((size_t)h * S + s) * CH + c) * NRES + nn] = f2bf(acc[j][i][r]);
                }
            }
    } else {
        #pragma unroll
        for (int i = 0; i < 4; ++i)
            #pragma unroll
            for (int r = 0; r < 4; ++r) {
                const int row = m0 + wm + i*16 + kg*4 + r;
                #pragma unroll
                for (int j = 0; j < 4; ++j) {
                    const int gc = n0 + wn + j*16 + rl - HC;
                    g_[(size_t)row * HC + gc] = f2bf(1.0f / (1.0f + expf(-acc[i][j][r])));
                }
            }
    }
}

// ---------------- MFMA einsum: o^T[c][q] = sum_k vt[h][s][c][k]*a[h][q][k] --
__global__ __launch_bounds__(256) void k_attn(const u16* __restrict__ a_,
        const u16* __restrict__ vt, u16* __restrict__ o_) {
    __shared__ u16 Vs[32][392];
    __shared__ u16 Qs[192][40];
    const int tid = threadIdx.x;
    const int b = blockIdx.x;
    const int qh = b & 1, s = (b >> 1) & 63, h = b >> 7;
    const int q0 = qh * 192;
    const int wave = tid >> 6, lane = tid & 63;
    const int rl = lane & 15, kg = lane >> 4;
    const u16* vbase = vt + ((size_t)(h * S + s) * CH) * NRES;
    #pragma unroll
    for (int t = 0; t < 6; ++t) {
        const int idx = tid + t * 256;            // 1536 chunks of 8
        const int c = idx / 48, kk = (idx % 48) * 8;
        *(ushort8*)&Vs[c][kk] = *(const ushort8*)&vbase[c * NRES + kk];
    }
    const u16* abase = a_ + (size_t)h * NRES * NRES + (size_t)q0 * NRES;
    const int qw = wave * 48;
    f32x4 acc[2][3] = {};
    for (int kt = 0; kt < NRES; kt += 32) {
        __syncthreads();
        #pragma unroll
        for (int t = 0; t < 3; ++t) {
            const int ci = tid + t * 256;         // 768 chunks of 8
            const int q = ci >> 2, kp = (ci & 3) * 8;
            *(ushort8*)&Qs[q][kp] = *(const ushort8*)&abase[(size_t)q * NRES + kt + kp];
        }
        __syncthreads();
        bf16x8 vf[2], qf[3];
        #pragma unroll
        for (int i = 0; i < 2; ++i) vf[i] = *(const bf16x8*)&Vs[i*16 + rl][kt + kg*8];
        #pragma unroll
        for (int j = 0; j < 3; ++j) qf[j] = *(const bf16x8*)&Qs[qw + j*16 + rl][kg*8];
        #pragma unroll
        for (int i = 0; i < 2; ++i)
            #pragma unroll
            for (int j = 0; j < 3; ++j)
                acc[i][j] = __builtin_amdgcn_mfma_f32_16x16x32_bf16(vf[i], qf[j], acc[i][j], 0, 0, 0);
    }
    #pragma unroll
    for (int i = 0; i < 2; ++i)
        #pragma unroll
        for (int j = 0; j < 3; ++j) {
            const int q = q0 + qw + j*16 + rl;
            const int c0 = i*16 + kg*4;
            u16 tmp[4];
            #pragma unroll
            for (int r = 0; r < 4; ++r) tmp[r] = f2bf(acc[i][j][r]);
            *(ushort4_t*)&o_[((size_t)s * NRES + q) * HC + h * CH + c0] = *(ushort4_t*)tmp;
        }
}

// ---------------- MFMA GEMM: out = (o*g) @ Wo -------------------------------
__global__ __launch_bounds__(256) void k_gemm_out(const u16* __restrict__ o_,
        const u16* __restrict__ g_, const u16* __restrict__ Wot,
        float* __restrict__ out) {
    __shared__ u16 As[128][40];
    __shared__ u16 Bs[128][40];
    const int tid = threadIdx.x;
    const int mt = blockIdx.x >> 1, nt = blockIdx.x & 1;
    const int m0 = mt * 128, n0 = nt * 128;
    const int wave = tid >> 6, lane = tid & 63;
    const int wm = (wave >> 1) * 64, wn = (wave & 1) * 64;
    const int rl = lane & 15, kg = lane >> 4;
    const int sr = tid >> 1, sh = (tid & 1) * 16;
    const u16* orow = o_ + (size_t)(m0 + sr) * HC;
    const u16* grow = g_ + (size_t)(m0 + sr) * HC;
    const u16* wrow = Wot + (size_t)(n0 + sr) * HC;
    f32x4 acc[4][4] = {};
    for (int kt = 0; kt < HC; kt += 32) {
        if (kt) __syncthreads();
        {
            u16 tmp[16];
            const ushort8 ov0 = *(const ushort8*)&orow[kt + sh];
            const ushort8 ov1 = *(const ushort8*)&orow[kt + sh + 8];
            const ushort8 gv0 = *(const ushort8*)&grow[kt + sh];
            const ushort8 gv1 = *(const ushort8*)&grow[kt + sh + 8];
            #pragma unroll
            for (int p = 0; p < 8; ++p) {
                tmp[p]     = f2bf(bf2f(ov0[p]) * bf2f(gv0[p]));
                tmp[p + 8] = f2bf(bf2f(ov1[p]) * bf2f(gv1[p]));
            }
            *(ushort8*)&As[sr][sh]     = *(ushort8*)&tmp[0];
            *(ushort8*)&As[sr][sh + 8] = *(ushort8*)&tmp[8];
            *(ushort8*)&Bs[sr][sh]     = *(const ushort8*)&wrow[kt + sh];
            *(ushort8*)&Bs[sr][sh + 8] = *(const ushort8*)&wrow[kt + sh + 8];
        }
        __syncthreads();
        bf16x8 af[4], bfr[4];
        #pragma unroll
        for (int i = 0; i < 4; ++i) af[i]  = *(const bf16x8*)&As[wm + i*16 + rl][kg*8];
        #pragma unroll
        for (int j = 0; j < 4; ++j) bfr[j] = *(const bf16x8*)&Bs[wn + j*16 + rl][kg*8];
        #pragma unroll
        for (int i = 0; i < 4; ++i)
            #pragma unroll
            for (int j = 0; j < 4; ++j)
                acc[i][j] = __builtin_amdgcn_mfma_f32_16x16x32_bf16(af[i], bfr[j], acc[i][j], 0, 0, 0);
    }
    #pragma unroll
    for (int i = 0; i < 4; ++i)
        #pragma unroll
        for (int r = 0; r < 4; ++r) {
            const int row = m0 + wm + i*16 + kg*4 + r;
            #pragma unroll
            for (int j = 0; j < 4; ++j)
                out[(size_t)row * CM + n0 + wn + j*16 + rl] = acc[i][j][r];
        }
}

extern "C" void kernel_launch(void* const* d_in, const int* in_sizes, int n_in,
                              void* d_out, int out_size, void* d_ws, size_t ws_size,
                              hipStream_t stream) {
    const float* m      = (const float*)d_in[0];
    const float* z      = (const float*)d_in[1];
    const float* mask   = (const float*)d_in[2];
    const float* ln_m_w = (const float*)d_in[3];
    const float* ln_m_b = (const float*)d_in[4];
    const float* ln_z_w = (const float*)d_in[5];
    const float* ln_z_b = (const float*)d_in[6];
    const float* Wz     = (const float*)d_in[7];
    const float* Wv     = (const float*)d_in[8];
    const float* Wg     = (const float*)d_in[9];
    const float* Wo     = (const float*)d_in[10];
    float* out = (float*)d_out;
    char* ws = (char*)d_ws;

    float* bias = (float*)(ws + OFF_BIAS);
    float* muw  = (float*)(ws + OFF_MU);
    float* rsw  = (float*)(ws + OFF_RS);
    u16* Wt     = (u16*)(ws + OFF_WT);
    u16* Wot    = (u16*)(ws + OFF_WOT);
    u16* a      = (u16*)(ws + OFF_A);
    u16* vtw    = (u16*)(ws + OFF_VT);
    u16* gw     = (u16*)(ws + OFF_G);
    u16* ow     = (u16*)(ws + OFF_O);
    float* zbw  = (float*)(ws + OFF_ZB);
    u16* WWT    = (u16*)(ws + OFF_WWT);
    float* C1   = (float*)(ws + OFF_C1);
    float* C2   = (float*)(ws + OFF_C2);

    k_bias<<<1, NRES, 0, stream>>>(mask, bias);
    k_prep_z<<<1, CZ, 0, stream>>>(Wz, ln_z_w, ln_z_b, WWT, C1, C2);
    k_zb<<<2304, 256, 0, stream>>>(z, WWT, C1, C2, zbw);
    k_soft<<<768, 256, 0, stream>>>(zbw, bias, a);
    k_prep_vg<<<512, 256, 0, stream>>>(Wv, Wg, Wt);
    k_prep_o<<<256, 256, 0, stream>>>(Wo, Wot);
    k_rowstats<<<(S * NRES) / 4, 256, 0, stream>>>(m, muw, rsw);
    k_gemm_vg<<<192 * 4, 256, 0, stream>>>(m, muw, rsw, ln_m_w, ln_m_b, Wt, vtw, gw);
    k_attn<<<NH * S * 2, 256, 0, stream>>>(a, vtw, ow);
    k_gemm_out<<<192 * 2, 256, 0, stream>>>(ow, gw, Wot, out);
}

// Round 4
// 103.897 us; speedup vs baseline: 3.1763x; 1.1687x over previous
//
#include <hip/hip_runtime.h>
#include <math.h>

#define S 64
#define NRES 384
#define CM 256
#define CZ 128
#define NH 8
#define CH 32
#define HC 256

typedef unsigned short u16;
typedef __attribute__((ext_vector_type(8))) short bf16x8;
typedef __attribute__((ext_vector_type(4))) float f32x4;
typedef __attribute__((ext_vector_type(8))) unsigned short ushort8;

// ---- workspace byte offsets ----
#define OFF_BIAS 0            // 384 f32
#define OFF_MU   4096         // 24576 f32
#define OFF_RS   102400       // 24576 f32
#define OFF_WT   200704       // 512*256 bf16 (Wv|Wg transposed)
#define OFF_WOT  462848       // 256*256 bf16 (Wo transposed)
#define OFF_A    593920       // 8*384*384 bf16
#define OFF_VT   2953216      // [h][s][c][n] 8*64*32*384 bf16
#define OFF_G    15536128     // 24576*256 bf16
#define OFF_O    28119040     // 24576*256 bf16
// overlapped (lifetimes disjoint in stream order):
#define OFF_ZB   OFF_O        // 147456*8 f32; dead before k_attn writes o
#define OFF_WWT  OFF_VT       // 16*128 bf16; dead before k_gemm_vg writes vt
#define OFF_C1   (OFF_VT + 4096)
#define OFF_C2   (OFF_VT + 4160)

__device__ __forceinline__ u16 f2bf(float f) {
    union { float f; unsigned int u; } v; v.f = f;
    unsigned int u = v.u;
    u += 0x7fff + ((u >> 16) & 1);
    return (u16)(u >> 16);
}
__device__ __forceinline__ float bf2f(u16 b) {
    union { float f; unsigned int u; } v; v.u = ((unsigned int)b) << 16;
    return v.f;
}

// ---------------- merged prep: bias | prep_z | Wt | Wot | rowstats ----------
// blocks: [0,2) bias; [2,3) prep_z; [3,515) Wt; [515,771) Wot; [771,6915) rowstats
__global__ __launch_bounds__(256) void k_prep_all(
        const float* __restrict__ mask, const float* __restrict__ Wz,
        const float* __restrict__ lzw, const float* __restrict__ lzb,
        const float* __restrict__ Wv, const float* __restrict__ Wg,
        const float* __restrict__ Wo, const float* __restrict__ m,
        float* __restrict__ bias, u16* __restrict__ WWT,
        float* __restrict__ C1, float* __restrict__ C2,
        u16* __restrict__ Wt, u16* __restrict__ Wot,
        float* __restrict__ mu_o, float* __restrict__ rs_o) {
    const int bid = blockIdx.x, tid = threadIdx.x;
    if (bid < 2) {
        const int k = bid * 256 + tid;
        if (k < NRES) {
            float mx = -1e30f;
            for (int s = 0; s < S; ++s) mx = fmaxf(mx, mask[s * NRES + k]);
            bias[k] = 1e9f * (mx - 1.0f);
        }
    } else if (bid == 2) {
        __shared__ float sW[CZ][NH], sB[CZ][NH];
        const int c = tid;
        if (c < CZ) {
            #pragma unroll
            for (int h = 0; h < NH; ++h) {
                const float wz = Wz[c * NH + h];
                const float ww = lzw[c] * wz;
                sW[c][h] = ww;
                sB[c][h] = lzb[c] * wz;
                WWT[h * CZ + c] = f2bf(ww);
                WWT[(NH + h) * CZ + c] = 0;
            }
        }
        __syncthreads();
        if (c < NH) {
            float s1 = 0.f, s2 = 0.f;
            for (int k = 0; k < CZ; ++k) { s1 += sW[k][c]; s2 += sB[k][c]; }
            C1[c] = s1; C2[c] = s2;
        } else if (c < 16) {
            C1[c] = 0.f; C2[c] = 0.f;
        }
    } else if (bid < 515) {
        const int i = (bid - 3) * 256 + tid;
        const int n = i >> 8, k = i & 255;
        const float v = (n < HC) ? Wv[(size_t)k * HC + n] : Wg[(size_t)k * HC + (n - HC)];
        Wt[i] = f2bf(v);
    } else if (bid < 771) {
        const int i = (bid - 515) * 256 + tid;
        const int n = i >> 8, k = i & 255;
        Wot[i] = f2bf(Wo[(size_t)k * CM + n]);
    } else {
        const int row = (bid - 771) * 4 + (tid >> 6);
        const int lane = tid & 63;
        const float4 x = *(const float4*)&m[(size_t)row * CM + lane * 4];
        float sm = x.x + x.y + x.z + x.w;
        float sq = x.x*x.x + x.y*x.y + x.z*x.z + x.w*x.w;
        #pragma unroll
        for (int off = 32; off >= 1; off >>= 1) {
            sm += __shfl_xor(sm, off);
            sq += __shfl_xor(sq, off);
        }
        if (lane == 0) {
            const float mu = sm * (1.0f / CM);
            const float var = sq * (1.0f / CM) - mu * mu;
            mu_o[row] = mu;
            rs_o[row] = rsqrtf(var + 1e-5f);
        }
    }
}

// ---------------- zb logits via MFMA: zb[row][h] ----------------------------
__global__ __launch_bounds__(256) void k_zb(const float* __restrict__ z,
        const u16* __restrict__ WWT, const float* __restrict__ C1,
        const float* __restrict__ C2, float* __restrict__ zb) {
    __shared__ float sMu[4][16], sRs[4][16];
    const int tid = threadIdx.x, wave = tid >> 6, lane = tid & 63;
    const int rl = lane & 15, kg = lane >> 4;
    const int row0 = blockIdx.x * 64 + wave * 16;
    const float* zrow = z + (size_t)(row0 + rl) * CZ + kg * 8;
    bf16x8 af[4];
    float sm = 0.f, sq = 0.f;
    #pragma unroll
    for (int t = 0; t < 4; ++t) {
        const float4 x0 = *(const float4*)&zrow[t * 32];
        const float4 x1 = *(const float4*)&zrow[t * 32 + 4];
        float xs[8] = {x0.x, x0.y, x0.z, x0.w, x1.x, x1.y, x1.z, x1.w};
        u16 tmp[8];
        #pragma unroll
        for (int e = 0; e < 8; ++e) {
            sm += xs[e]; sq += xs[e] * xs[e];
            tmp[e] = f2bf(xs[e]);
        }
        af[t] = *(bf16x8*)tmp;
    }
    sm += __shfl_xor(sm, 16); sq += __shfl_xor(sq, 16);
    sm += __shfl_xor(sm, 32); sq += __shfl_xor(sq, 32);
    const float mu = sm * (1.0f / CZ);
    const float var = sq * (1.0f / CZ) - mu * mu;
    const float rs = rsqrtf(var + 1e-5f);
    if (lane < 16) { sMu[wave][lane] = mu; sRs[wave][lane] = rs; }
    const u16* wbase = WWT + rl * CZ + kg * 8;
    bf16x8 bfr[4];
    #pragma unroll
    for (int t = 0; t < 4; ++t) bfr[t] = *(const bf16x8*)&wbase[t * 32];
    f32x4 acc = {};
    #pragma unroll
    for (int t = 0; t < 4; ++t)
        acc = __builtin_amdgcn_mfma_f32_16x16x32_bf16(af[t], bfr[t], acc, 0, 0, 0);
    __syncthreads();
    const float c1 = C1[rl], c2 = C2[rl];
    #pragma unroll
    for (int r = 0; r < 4; ++r) {
        const int rr = kg * 4 + r;
        const float p = sRs[wave][rr] * (acc[r] - sMu[wave][rr] * c1) + c2;
        if (rl < 8) zb[(size_t)(row0 + rr) * NH + rl] = p;
    }
}

// ---------------- softmax over k: a[h][q][k] bf16 ---------------------------
__global__ __launch_bounds__(256) void k_soft(const float* __restrict__ zb,
        const float* __restrict__ bias, u16* __restrict__ a_out) {
    const int w = blockIdx.x * 4 + (threadIdx.x >> 6);
    const int lane = threadIdx.x & 63;
    const int h = w & 7, q = w >> 3;
    float v[6];
    float mx = -1e30f;
    #pragma unroll
    for (int t = 0; t < 6; ++t) {
        const int k = lane + 64 * t;
        v[t] = zb[((size_t)q * NRES + k) * NH + h] + bias[k];
        mx = fmaxf(mx, v[t]);
    }
    #pragma unroll
    for (int off = 32; off >= 1; off >>= 1) mx = fmaxf(mx, __shfl_xor(mx, off));
    float sum = 0.f;
    #pragma unroll
    for (int t = 0; t < 6; ++t) { v[t] = expf(v[t] - mx); sum += v[t]; }
    #pragma unroll
    for (int off = 32; off >= 1; off >>= 1) sum += __shfl_xor(sum, off);
    const float inv = 1.0f / sum;
    #pragma unroll
    for (int t = 0; t < 6; ++t)
        a_out[((size_t)h * NRES + q) * NRES + lane + 64 * t] = f2bf(v[t] * inv);
}

// ---------------- MFMA GEMM: [LN(m)]@[Wv|Wg] -> vt + g ----------------------
__global__ __launch_bounds__(256) void k_gemm_vg(const float* __restrict__ m,
        const float* __restrict__ mu_, const float* __restrict__ rs_,
        const float* __restrict__ lw, const float* __restrict__ lb,
        const u16* __restrict__ Wt, u16* __restrict__ vt, u16* __restrict__ g_) {
    __shared__ u16 As[128][40];
    __shared__ u16 Bs[128][40];
    __shared__ float sLw[CM], sLb[CM];
    const int tid = threadIdx.x;
    const int mt = blockIdx.x >> 2, nt = blockIdx.x & 3;
    const int m0 = mt * 128, n0 = nt * 128;
    sLw[tid] = lw[tid]; sLb[tid] = lb[tid];
    const int wave = tid >> 6, lane = tid & 63;
    const int wm = (wave >> 1) * 64, wn = (wave & 1) * 64;
    const int rl = lane & 15, kg = lane >> 4;
    const int sr = tid >> 1, sh = (tid & 1) * 16;
    const float* mrow = m + (size_t)(m0 + sr) * CM;
    const float muv = mu_[m0 + sr], rsv = rs_[m0 + sr];
    const u16* wrow = Wt + (size_t)(n0 + sr) * CM;
    const bool vhalf = (n0 < HC);
    f32x4 acc[4][4] = {};
    __syncthreads();
    for (int kt = 0; kt < CM; kt += 32) {
        if (kt) __syncthreads();
        {
            u16 tmp[16];
            #pragma unroll
            for (int p = 0; p < 4; ++p) {
                const float4 x = *(const float4*)&mrow[kt + sh + p*4];
                const int kb = kt + sh + p*4;
                tmp[p*4+0] = f2bf((x.x - muv) * rsv * sLw[kb+0] + sLb[kb+0]);
                tmp[p*4+1] = f2bf((x.y - muv) * rsv * sLw[kb+1] + sLb[kb+1]);
                tmp[p*4+2] = f2bf((x.z - muv) * rsv * sLw[kb+2] + sLb[kb+2]);
                tmp[p*4+3] = f2bf((x.w - muv) * rsv * sLw[kb+3] + sLb[kb+3]);
            }
            *(ushort8*)&As[sr][sh]     = *(ushort8*)&tmp[0];
            *(ushort8*)&As[sr][sh + 8] = *(ushort8*)&tmp[8];
            *(ushort8*)&Bs[sr][sh]     = *(const ushort8*)&wrow[kt + sh];
            *(ushort8*)&Bs[sr][sh + 8] = *(const ushort8*)&wrow[kt + sh + 8];
        }
        __syncthreads();
        bf16x8 af[4], bfr[4];
        #pragma unroll
        for (int i = 0; i < 4; ++i) af[i]  = *(const bf16x8*)&As[wm + i*16 + rl][kg*8];
        #pragma unroll
        for (int j = 0; j < 4; ++j) bfr[j] = *(const bf16x8*)&Bs[wn + j*16 + rl][kg*8];
        if (vhalf) {
            #pragma unroll
            for (int j = 0; j < 4; ++j)
                #pragma unroll
                for (int i = 0; i < 4; ++i)
                    acc[j][i] = __builtin_amdgcn_mfma_f32_16x16x32_bf16(bfr[j], af[i], acc[j][i], 0, 0, 0);
        } else {
            #pragma unroll
            for (int i = 0; i < 4; ++i)
                #pragma unroll
                for (int j = 0; j < 4; ++j)
                    acc[i][j] = __builtin_amdgcn_mfma_f32_16x16x32_bf16(af[i], bfr[j], acc[i][j], 0, 0, 0);
        }
    }
    if (vhalf) {
        #pragma unroll
        for (int j = 0; j < 4; ++j)
            #pragma unroll
            for (int r = 0; r < 4; ++r) {
                const int vcol = n0 + wn + j*16 + kg*4 + r;
                const int h = vcol >> 5, c = vcol & 31;
                #pragma unroll
                for (int i = 0; i < 4; ++i) {
                    const int mrowb = m0 + wm + i*16;
                    const int s = mrowb / NRES;
                    const int nn = mrowb - s * NRES + rl;
                    vt[(((size_t)h * S + s) * CH + c) * NRES + nn] = f2bf(acc[j][i][r]);
                }
            }
    } else {
        #pragma unroll
        for (int i = 0; i < 4; ++i)
            #pragma unroll
            for (int r = 0; r < 4; ++r) {
                const int row = m0 + wm + i*16 + kg*4 + r;
                #pragma unroll
                for (int j = 0; j < 4; ++j) {
                    const int gc = n0 + wn + j*16 + rl - HC;
                    g_[(size_t)row * HC + gc] = f2bf(1.0f / (1.0f + expf(-acc[i][j][r])));
                }
            }
    }
}

// ---------------- attn as per-h GEMM: C[q][(s,c)] = sum_n a[h,q,n] vt[h,sc,n]
// grid: h(8) x mt(3) x nt(16) = 384 blocks. 128x128 tile, K=384.
__global__ __launch_bounds__(256) void k_attn2(const u16* __restrict__ a_,
        const u16* __restrict__ vt, u16* __restrict__ o_) {
    __shared__ u16 As[128][40];
    __shared__ u16 Bs[128][40];
    const int tid = threadIdx.x;
    const int b = blockIdx.x;
    const int h = b / 48, rem = b - h * 48;
    const int mt = rem >> 4, nt = rem & 15;
    const int q0 = mt * 128, sc0 = nt * 128;
    const int wave = tid >> 6, lane = tid & 63;
    const int wm = (wave >> 1) * 64, wn = (wave & 1) * 64;
    const int rl = lane & 15, kg = lane >> 4;
    const int sr = tid >> 1, sh = (tid & 1) * 16;
    const u16* arow = a_ + (size_t)h * NRES * NRES + (size_t)(q0 + sr) * NRES;
    const u16* vrow = vt + (size_t)h * S * CH * NRES + (size_t)(sc0 + sr) * NRES;
    f32x4 acc[4][4] = {};
    for (int kt = 0; kt < NRES; kt += 32) {
        if (kt) __syncthreads();
        *(ushort8*)&As[sr][sh]     = *(const ushort8*)&arow[kt + sh];
        *(ushort8*)&As[sr][sh + 8] = *(const ushort8*)&arow[kt + sh + 8];
        *(ushort8*)&Bs[sr][sh]     = *(const ushort8*)&vrow[kt + sh];
        *(ushort8*)&Bs[sr][sh + 8] = *(const ushort8*)&vrow[kt + sh + 8];
        __syncthreads();
        bf16x8 af[4], bfr[4];
        #pragma unroll
        for (int i = 0; i < 4; ++i) af[i]  = *(const bf16x8*)&As[wm + i*16 + rl][kg*8];
        #pragma unroll
        for (int j = 0; j < 4; ++j) bfr[j] = *(const bf16x8*)&Bs[wn + j*16 + rl][kg*8];
        #pragma unroll
        for (int i = 0; i < 4; ++i)
            #pragma unroll
            for (int j = 0; j < 4; ++j)
                acc[i][j] = __builtin_amdgcn_mfma_f32_16x16x32_bf16(af[i], bfr[j], acc[i][j], 0, 0, 0);
    }
    #pragma unroll
    for (int i = 0; i < 4; ++i)
        #pragma unroll
        for (int r = 0; r < 4; ++r) {
            const int q = q0 + wm + i*16 + kg*4 + r;
            #pragma unroll
            for (int j = 0; j < 4; ++j) {
                const int sc = sc0 + wn + j*16 + rl;
                const int s = sc >> 5, c = sc & 31;
                o_[(((size_t)s * NRES + q) * NH + h) * CH + c] = f2bf(acc[i][j][r]);
            }
        }
}

// ---------------- MFMA GEMM: out = (o*g) @ Wo -------------------------------
__global__ __launch_bounds__(256) void k_gemm_out(const u16* __restrict__ o_,
        const u16* __restrict__ g_, const u16* __restrict__ Wot,
        float* __restrict__ out) {
    __shared__ u16 As[128][40];
    __shared__ u16 Bs[128][40];
    const int tid = threadIdx.x;
    const int mt = blockIdx.x >> 1, nt = blockIdx.x & 1;
    const int m0 = mt * 128, n0 = nt * 128;
    const int wave = tid >> 6, lane = tid & 63;
    const int wm = (wave >> 1) * 64, wn = (wave & 1) * 64;
    const int rl = lane & 15, kg = lane >> 4;
    const int sr = tid >> 1, sh = (tid & 1) * 16;
    const u16* orow = o_ + (size_t)(m0 + sr) * HC;
    const u16* grow = g_ + (size_t)(m0 + sr) * HC;
    const u16* wrow = Wot + (size_t)(n0 + sr) * HC;
    f32x4 acc[4][4] = {};
    for (int kt = 0; kt < HC; kt += 32) {
        if (kt) __syncthreads();
        {
            u16 tmp[16];
            const ushort8 ov0 = *(const ushort8*)&orow[kt + sh];
            const ushort8 ov1 = *(const ushort8*)&orow[kt + sh + 8];
            const ushort8 gv0 = *(const ushort8*)&grow[kt + sh];
            const ushort8 gv1 = *(const ushort8*)&grow[kt + sh + 8];
            #pragma unroll
            for (int p = 0; p < 8; ++p) {
                tmp[p]     = f2bf(bf2f(ov0[p]) * bf2f(gv0[p]));
                tmp[p + 8] = f2bf(bf2f(ov1[p]) * bf2f(gv1[p]));
            }
            *(ushort8*)&As[sr][sh]     = *(ushort8*)&tmp[0];
            *(ushort8*)&As[sr][sh + 8] = *(ushort8*)&tmp[8];
            *(ushort8*)&Bs[sr][sh]     = *(const ushort8*)&wrow[kt + sh];
            *(ushort8*)&Bs[sr][sh + 8] = *(const ushort8*)&wrow[kt + sh + 8];
        }
        __syncthreads();
        bf16x8 af[4], bfr[4];
        #pragma unroll
        for (int i = 0; i < 4; ++i) af[i]  = *(const bf16x8*)&As[wm + i*16 + rl][kg*8];
        #pragma unroll
        for (int j = 0; j < 4; ++j) bfr[j] = *(const bf16x8*)&Bs[wn + j*16 + rl][kg*8];
        #pragma unroll
        for (int i = 0; i < 4; ++i)
            #pragma unroll
            for (int j = 0; j < 4; ++j)
                acc[i][j] = __builtin_amdgcn_mfma_f32_16x16x32_bf16(af[i], bfr[j], acc[i][j], 0, 0, 0);
    }
    #pragma unroll
    for (int i = 0; i < 4; ++i)
        #pragma unroll
        for (int r = 0; r < 4; ++r) {
            const int row = m0 + wm + i*16 + kg*4 + r;
            #pragma unroll
            for (int j = 0; j < 4; ++j)
                out[(size_t)row * CM + n0 + wn + j*16 + rl] = acc[i][j][r];
        }
}

extern "C" void kernel_launch(void* const* d_in, const int* in_sizes, int n_in,
                              void* d_out, int out_size, void* d_ws, size_t ws_size,
                              hipStream_t stream) {
    const float* m      = (const float*)d_in[0];
    const float* z      = (const float*)d_in[1];
    const float* mask   = (const float*)d_in[2];
    const float* ln_m_w = (const float*)d_in[3];
    const float* ln_m_b = (const float*)d_in[4];
    const float* ln_z_w = (const float*)d_in[5];
    const float* ln_z_b = (const float*)d_in[6];
    const float* Wz     = (const float*)d_in[7];
    const float* Wv     = (const float*)d_in[8];
    const float* Wg     = (const float*)d_in[9];
    const float* Wo     = (const float*)d_in[10];
    float* out = (float*)d_out;
    char* ws = (char*)d_ws;

    float* bias = (float*)(ws + OFF_BIAS);
    float* muw  = (float*)(ws + OFF_MU);
    float* rsw  = (float*)(ws + OFF_RS);
    u16* Wt     = (u16*)(ws + OFF_WT);
    u16* Wot    = (u16*)(ws + OFF_WOT);
    u16* a      = (u16*)(ws + OFF_A);
    u16* vtw    = (u16*)(ws + OFF_VT);
    u16* gw     = (u16*)(ws + OFF_G);
    u16* ow     = (u16*)(ws + OFF_O);
    float* zbw  = (float*)(ws + OFF_ZB);
    u16* WWT    = (u16*)(ws + OFF_WWT);
    float* C1   = (float*)(ws + OFF_C1);
    float* C2   = (float*)(ws + OFF_C2);

    k_prep_all<<<6915, 256, 0, stream>>>(mask, Wz, ln_z_w, ln_z_b, Wv, Wg, Wo, m,
                                         bias, WWT, C1, C2, Wt, Wot, muw, rsw);
    k_zb<<<2304, 256, 0, stream>>>(z, WWT, C1, C2, zbw);
    k_soft<<<768, 256, 0, stream>>>(zbw, bias, a);
    k_gemm_vg<<<192 * 4, 256, 0, stream>>>(m, muw, rsw, ln_m_w, ln_m_b, Wt, vtw, gw);
    k_attn2<<<384, 256, 0, stream>>>(a, vtw, ow);
    k_gemm_out<<<192 * 2, 256, 0, stream>>>(ow, gw, Wot, out);
}

// Round 5
// 90.300 us; speedup vs baseline: 3.6546x; 1.1506x over previous
//
#include <hip/hip_runtime.h>
#include <math.h>

#define S 64
#define NRES 384
#define CM 256
#define CZ 128
#define NH 8
#define CH 32
#define HC 256

typedef unsigned short u16;
typedef __attribute__((ext_vector_type(8))) short bf16x8;
typedef __attribute__((ext_vector_type(4))) float f32x4;
typedef __attribute__((ext_vector_type(8))) unsigned short ushort8;
typedef __attribute__((ext_vector_type(4))) unsigned short ushort4_t;

// ---- workspace byte offsets ----
#define OFF_BIAS 0            // 384 f32
#define OFF_WT   200704       // 512*256 bf16 (Wv|Wg transposed)
#define OFF_WOT  462848       // 256*256 bf16 (Wo transposed)
#define OFF_A    593920       // 8*384*384 bf16
#define OFF_VT   2953216      // [h][s][c][n] 8*64*32*384 bf16
#define OFF_G    15536128     // 24576*256 bf16
#define OFF_O    28119040     // 24576*256 bf16
#define OFF_MLN  40701952     // 24576*256 bf16 (LN(m) pre-cast)
// overlapped (lifetimes disjoint in stream order):
#define OFF_ZB   OFF_O        // 147456*8 f32; dead before k_attn2 writes o
#define OFF_WWT  OFF_VT       // 16*128 bf16; dead before k_gemm_vg writes vt
#define OFF_C1   (OFF_VT + 4096)
#define OFF_C2   (OFF_VT + 4160)

__device__ __forceinline__ u16 f2bf(float f) {
    union { float f; unsigned int u; } v; v.f = f;
    unsigned int u = v.u;
    u += 0x7fff + ((u >> 16) & 1);
    return (u16)(u >> 16);
}
__device__ __forceinline__ float bf2f(u16 b) {
    union { float f; unsigned int u; } v; v.u = ((unsigned int)b) << 16;
    return v.f;
}

// ---------------- merged prep: bias | prep_z | Wt | Wot | LN(m)->bf16 -------
// blocks: [0,2) bias; [2,3) prep_z; [3,515) Wt; [515,771) Wot; [771,6915) m_ln
__global__ __launch_bounds__(256) void k_prep_all(
        const float* __restrict__ mask, const float* __restrict__ Wz,
        const float* __restrict__ lzw, const float* __restrict__ lzb,
        const float* __restrict__ Wv, const float* __restrict__ Wg,
        const float* __restrict__ Wo, const float* __restrict__ m,
        const float* __restrict__ lmw, const float* __restrict__ lmb,
        float* __restrict__ bias, u16* __restrict__ WWT,
        float* __restrict__ C1, float* __restrict__ C2,
        u16* __restrict__ Wt, u16* __restrict__ Wot,
        u16* __restrict__ mln) {
    const int bid = blockIdx.x, tid = threadIdx.x;
    if (bid < 2) {
        const int k = bid * 256 + tid;
        if (k < NRES) {
            float mx = -1e30f;
            for (int s = 0; s < S; ++s) mx = fmaxf(mx, mask[s * NRES + k]);
            bias[k] = 1e9f * (mx - 1.0f);
        }
    } else if (bid == 2) {
        __shared__ float sW[CZ][NH], sB[CZ][NH];
        const int c = tid;
        if (c < CZ) {
            #pragma unroll
            for (int h = 0; h < NH; ++h) {
                const float wz = Wz[c * NH + h];
                const float ww = lzw[c] * wz;
                sW[c][h] = ww;
                sB[c][h] = lzb[c] * wz;
                WWT[h * CZ + c] = f2bf(ww);
                WWT[(NH + h) * CZ + c] = 0;
            }
        }
        __syncthreads();
        if (c < NH) {
            float s1 = 0.f, s2 = 0.f;
            for (int k = 0; k < CZ; ++k) { s1 += sW[k][c]; s2 += sB[k][c]; }
            C1[c] = s1; C2[c] = s2;
        } else if (c < 16) {
            C1[c] = 0.f; C2[c] = 0.f;
        }
    } else if (bid < 515) {
        const int i = (bid - 3) * 256 + tid;
        const int n = i >> 8, k = i & 255;
        const float v = (n < HC) ? Wv[(size_t)k * HC + n] : Wg[(size_t)k * HC + (n - HC)];
        Wt[i] = f2bf(v);
    } else if (bid < 771) {
        const int i = (bid - 515) * 256 + tid;
        const int n = i >> 8, k = i & 255;
        Wot[i] = f2bf(Wo[(size_t)k * CM + n]);
    } else {
        const int row = (bid - 771) * 4 + (tid >> 6);
        const int lane = tid & 63;
        const float4 x = *(const float4*)&m[(size_t)row * CM + lane * 4];
        float sm = x.x + x.y + x.z + x.w;
        float sq = x.x*x.x + x.y*x.y + x.z*x.z + x.w*x.w;
        #pragma unroll
        for (int off = 32; off >= 1; off >>= 1) {
            sm += __shfl_xor(sm, off);
            sq += __shfl_xor(sq, off);
        }
        const float mu = sm * (1.0f / CM);
        const float var = sq * (1.0f / CM) - mu * mu;
        const float rs = rsqrtf(var + 1e-5f);
        const float4 w4 = *(const float4*)&lmw[lane * 4];
        const float4 b4 = *(const float4*)&lmb[lane * 4];
        u16 t4[4];
        t4[0] = f2bf((x.x - mu) * rs * w4.x + b4.x);
        t4[1] = f2bf((x.y - mu) * rs * w4.y + b4.y);
        t4[2] = f2bf((x.z - mu) * rs * w4.z + b4.z);
        t4[3] = f2bf((x.w - mu) * rs * w4.w + b4.w);
        *(ushort4_t*)&mln[(size_t)row * CM + lane * 4] = *(ushort4_t*)t4;
    }
}

// ---------------- zb logits via MFMA: zb[row][h] ----------------------------
__global__ __launch_bounds__(256) void k_zb(const float* __restrict__ z,
        const u16* __restrict__ WWT, const float* __restrict__ C1,
        const float* __restrict__ C2, float* __restrict__ zb) {
    __shared__ float sMu[4][16], sRs[4][16];
    const int tid = threadIdx.x, wave = tid >> 6, lane = tid & 63;
    const int rl = lane & 15, kg = lane >> 4;
    const int row0 = blockIdx.x * 64 + wave * 16;
    const float* zrow = z + (size_t)(row0 + rl) * CZ + kg * 8;
    bf16x8 af[4];
    float sm = 0.f, sq = 0.f;
    #pragma unroll
    for (int t = 0; t < 4; ++t) {
        const float4 x0 = *(const float4*)&zrow[t * 32];
        const float4 x1 = *(const float4*)&zrow[t * 32 + 4];
        float xs[8] = {x0.x, x0.y, x0.z, x0.w, x1.x, x1.y, x1.z, x1.w};
        u16 tmp[8];
        #pragma unroll
        for (int e = 0; e < 8; ++e) {
            sm += xs[e]; sq += xs[e] * xs[e];
            tmp[e] = f2bf(xs[e]);
        }
        af[t] = *(bf16x8*)tmp;
    }
    sm += __shfl_xor(sm, 16); sq += __shfl_xor(sq, 16);
    sm += __shfl_xor(sm, 32); sq += __shfl_xor(sq, 32);
    const float mu = sm * (1.0f / CZ);
    const float var = sq * (1.0f / CZ) - mu * mu;
    const float rs = rsqrtf(var + 1e-5f);
    if (lane < 16) { sMu[wave][lane] = mu; sRs[wave][lane] = rs; }
    const u16* wbase = WWT + rl * CZ + kg * 8;
    bf16x8 bfr[4];
    #pragma unroll
    for (int t = 0; t < 4; ++t) bfr[t] = *(const bf16x8*)&wbase[t * 32];
    f32x4 acc = {};
    #pragma unroll
    for (int t = 0; t < 4; ++t)
        acc = __builtin_amdgcn_mfma_f32_16x16x32_bf16(af[t], bfr[t], acc, 0, 0, 0);
    __syncthreads();
    const float c1 = C1[rl], c2 = C2[rl];
    #pragma unroll
    for (int r = 0; r < 4; ++r) {
        const int rr = kg * 4 + r;
        const float p = sRs[wave][rr] * (acc[r] - sMu[wave][rr] * c1) + c2;
        if (rl < 8) zb[(size_t)(row0 + rr) * NH + rl] = p;
    }
}

// ---------------- softmax over k: a[h][q][k] bf16 ---------------------------
__global__ __launch_bounds__(256) void k_soft(const float* __restrict__ zb,
        const float* __restrict__ bias, u16* __restrict__ a_out) {
    const int w = blockIdx.x * 4 + (threadIdx.x >> 6);
    const int lane = threadIdx.x & 63;
    const int h = w & 7, q = w >> 3;
    float v[6];
    float mx = -1e30f;
    #pragma unroll
    for (int t = 0; t < 6; ++t) {
        const int k = lane + 64 * t;
        v[t] = zb[((size_t)q * NRES + k) * NH + h] + bias[k];
        mx = fmaxf(mx, v[t]);
    }
    #pragma unroll
    for (int off = 32; off >= 1; off >>= 1) mx = fmaxf(mx, __shfl_xor(mx, off));
    float sum = 0.f;
    #pragma unroll
    for (int t = 0; t < 6; ++t) { v[t] = expf(v[t] - mx); sum += v[t]; }
    #pragma unroll
    for (int off = 32; off >= 1; off >>= 1) sum += __shfl_xor(sum, off);
    const float inv = 1.0f / sum;
    #pragma unroll
    for (int t = 0; t < 6; ++t)
        a_out[((size_t)h * NRES + q) * NRES + lane + 64 * t] = f2bf(v[t] * inv);
}

// ---------------- MFMA GEMM: m_ln @ [Wv|Wg] -> vt + g  (XCD-swizzled) -------
__global__ __launch_bounds__(256) void k_gemm_vg(const u16* __restrict__ mln,
        const u16* __restrict__ Wt, u16* __restrict__ vt, u16* __restrict__ g_) {
    __shared__ u16 As[128][40];
    __shared__ u16 Bs[128][40];
    const int tid = threadIdx.x;
    // swizzle: 4 nt-siblings of one mt-strip land on one XCD
    const int xcd = blockIdx.x & 7, idx = blockIdx.x >> 3;
    const int nt = idx & 3, mt = xcd * 24 + (idx >> 2);
    const int m0 = mt * 128, n0 = nt * 128;
    const int wave = tid >> 6, lane = tid & 63;
    const int wm = (wave >> 1) * 64, wn = (wave & 1) * 64;
    const int rl = lane & 15, kg = lane >> 4;
    const int sr = tid >> 1, sh = (tid & 1) * 16;
    const u16* arow = mln + (size_t)(m0 + sr) * CM;
    const u16* wrow = Wt + (size_t)(n0 + sr) * CM;
    const bool vhalf = (n0 < HC);
    f32x4 acc[4][4] = {};
    for (int kt = 0; kt < CM; kt += 32) {
        if (kt) __syncthreads();
        *(ushort8*)&As[sr][sh]     = *(const ushort8*)&arow[kt + sh];
        *(ushort8*)&As[sr][sh + 8] = *(const ushort8*)&arow[kt + sh + 8];
        *(ushort8*)&Bs[sr][sh]     = *(const ushort8*)&wrow[kt + sh];
        *(ushort8*)&Bs[sr][sh + 8] = *(const ushort8*)&wrow[kt + sh + 8];
        __syncthreads();
        bf16x8 af[4], bfr[4];
        #pragma unroll
        for (int i = 0; i < 4; ++i) af[i]  = *(const bf16x8*)&As[wm + i*16 + rl][kg*8];
        #pragma unroll
        for (int j = 0; j < 4; ++j) bfr[j] = *(const bf16x8*)&Bs[wn + j*16 + rl][kg*8];
        if (vhalf) {
            #pragma unroll
            for (int j = 0; j < 4; ++j)
                #pragma unroll
                for (int i = 0; i < 4; ++i)
                    acc[j][i] = __builtin_amdgcn_mfma_f32_16x16x32_bf16(bfr[j], af[i], acc[j][i], 0, 0, 0);
        } else {
            #pragma unroll
            for (int i = 0; i < 4; ++i)
                #pragma unroll
                for (int j = 0; j < 4; ++j)
                    acc[i][j] = __builtin_amdgcn_mfma_f32_16x16x32_bf16(af[i], bfr[j], acc[i][j], 0, 0, 0);
        }
    }
    if (vhalf) {
        #pragma unroll
        for (int j = 0; j < 4; ++j)
            #pragma unroll
            for (int r = 0; r < 4; ++r) {
                const int vcol = n0 + wn + j*16 + kg*4 + r;
                const int h = vcol >> 5, c = vcol & 31;
                #pragma unroll
                for (int i = 0; i < 4; ++i) {
                    const int mrowb = m0 + wm + i*16;
                    const int s = mrowb / NRES;
                    const int nn = mrowb - s * NRES + rl;
                    vt[(((size_t)h * S + s) * CH + c) * NRES + nn] = f2bf(acc[j][i][r]);
                }
            }
    } else {
        #pragma unroll
        for (int i = 0; i < 4; ++i)
            #pragma unroll
            for (int r = 0; r < 4; ++r) {
                const int row = m0 + wm + i*16 + kg*4 + r;
                #pragma unroll
                for (int j = 0; j < 4; ++j) {
                    const int gc = n0 + wn + j*16 + rl - HC;
                    g_[(size_t)row * HC + gc] = f2bf(1.0f / (1.0f + expf(-acc[i][j][r])));
                }
            }
    }
}

// ---------------- attn as per-h GEMM (one head per XCD) ---------------------
__global__ __launch_bounds__(256) void k_attn2(const u16* __restrict__ a_,
        const u16* __restrict__ vt, u16* __restrict__ o_) {
    __shared__ u16 As[128][40];
    __shared__ u16 Bs[128][40];
    const int tid = threadIdx.x;
    // swizzle: h = bid&7 so each head's 48 blocks share one XCD's L2
    const int h = blockIdx.x & 7, rem = blockIdx.x >> 3;
    const int mt = rem >> 4, nt = rem & 15;
    const int q0 = mt * 128, sc0 = nt * 128;
    const int wave = tid >> 6, lane = tid & 63;
    const int wm = (wave >> 1) * 64, wn = (wave & 1) * 64;
    const int rl = lane & 15, kg = lane >> 4;
    const int sr = tid >> 1, sh = (tid & 1) * 16;
    const u16* arow = a_ + (size_t)h * NRES * NRES + (size_t)(q0 + sr) * NRES;
    const u16* vrow = vt + (size_t)h * S * CH * NRES + (size_t)(sc0 + sr) * NRES;
    f32x4 acc[4][4] = {};
    for (int kt = 0; kt < NRES; kt += 32) {
        if (kt) __syncthreads();
        *(ushort8*)&As[sr][sh]     = *(const ushort8*)&arow[kt + sh];
        *(ushort8*)&As[sr][sh + 8] = *(const ushort8*)&arow[kt + sh + 8];
        *(ushort8*)&Bs[sr][sh]     = *(const ushort8*)&vrow[kt + sh];
        *(ushort8*)&Bs[sr][sh + 8] = *(const ushort8*)&vrow[kt + sh + 8];
        __syncthreads();
        bf16x8 af[4], bfr[4];
        #pragma unroll
        for (int i = 0; i < 4; ++i) af[i]  = *(const bf16x8*)&As[wm + i*16 + rl][kg*8];
        #pragma unroll
        for (int j = 0; j < 4; ++j) bfr[j] = *(const bf16x8*)&Bs[wn + j*16 + rl][kg*8];
        #pragma unroll
        for (int i = 0; i < 4; ++i)
            #pragma unroll
            for (int j = 0; j < 4; ++j)
                acc[i][j] = __builtin_amdgcn_mfma_f32_16x16x32_bf16(af[i], bfr[j], acc[i][j], 0, 0, 0);
    }
    #pragma unroll
    for (int i = 0; i < 4; ++i)
        #pragma unroll
        for (int r = 0; r < 4; ++r) {
            const int q = q0 + wm + i*16 + kg*4 + r;
            #pragma unroll
            for (int j = 0; j < 4; ++j) {
                const int sc = sc0 + wn + j*16 + rl;
                const int s = sc >> 5, c = sc & 31;
                o_[(((size_t)s * NRES + q) * NH + h) * CH + c] = f2bf(acc[i][j][r]);
            }
        }
}

// ---------------- MFMA GEMM: out = (o*g) @ Wo  (XCD-swizzled) ---------------
__global__ __launch_bounds__(256) void k_gemm_out(const u16* __restrict__ o_,
        const u16* __restrict__ g_, const u16* __restrict__ Wot,
        float* __restrict__ out) {
    __shared__ u16 As[128][40];
    __shared__ u16 Bs[128][40];
    const int tid = threadIdx.x;
    const int xcd = blockIdx.x & 7, idx = blockIdx.x >> 3;
    const int nt = idx & 1, mt = xcd * 24 + (idx >> 1);
    const int m0 = mt * 128, n0 = nt * 128;
    const int wave = tid >> 6, lane = tid & 63;
    const int wm = (wave >> 1) * 64, wn = (wave & 1) * 64;
    const int rl = lane & 15, kg = lane >> 4;
    const int sr = tid >> 1, sh = (tid & 1) * 16;
    const u16* orow = o_ + (size_t)(m0 + sr) * HC;
    const u16* grow = g_ + (size_t)(m0 + sr) * HC;
    const u16* wrow = Wot + (size_t)(n0 + sr) * HC;
    f32x4 acc[4][4] = {};
    for (int kt = 0; kt < HC; kt += 32) {
        if (kt) __syncthreads();
        {
            u16 tmp[16];
            const ushort8 ov0 = *(const ushort8*)&orow[kt + sh];
            const ushort8 ov1 = *(const ushort8*)&orow[kt + sh + 8];
            const ushort8 gv0 = *(const ushort8*)&grow[kt + sh];
            const ushort8 gv1 = *(const ushort8*)&grow[kt + sh + 8];
            #pragma unroll
            for (int p = 0; p < 8; ++p) {
                tmp[p]     = f2bf(bf2f(ov0[p]) * bf2f(gv0[p]));
                tmp[p + 8] = f2bf(bf2f(ov1[p]) * bf2f(gv1[p]));
            }
            *(ushort8*)&As[sr][sh]     = *(ushort8*)&tmp[0];
            *(ushort8*)&As[sr][sh + 8] = *(ushort8*)&tmp[8];
            *(ushort8*)&Bs[sr][sh]     = *(const ushort8*)&wrow[kt + sh];
            *(ushort8*)&Bs[sr][sh + 8] = *(const ushort8*)&wrow[kt + sh + 8];
        }
        __syncthreads();
        bf16x8 af[4], bfr[4];
        #pragma unroll
        for (int i = 0; i < 4; ++i) af[i]  = *(const bf16x8*)&As[wm + i*16 + rl][kg*8];
        #pragma unroll
        for (int j = 0; j < 4; ++j) bfr[j] = *(const bf16x8*)&Bs[wn + j*16 + rl][kg*8];
        #pragma unroll
        for (int i = 0; i < 4; ++i)
            #pragma unroll
            for (int j = 0; j < 4; ++j)
                acc[i][j] = __builtin_amdgcn_mfma_f32_16x16x32_bf16(af[i], bfr[j], acc[i][j], 0, 0, 0);
    }
    #pragma unroll
    for (int i = 0; i < 4; ++i)
        #pragma unroll
        for (int r = 0; r < 4; ++r) {
            const int row = m0 + wm + i*16 + kg*4 + r;
            #pragma unroll
            for (int j = 0; j < 4; ++j)
                out[(size_t)row * CM + n0 + wn + j*16 + rl] = acc[i][j][r];
        }
}

extern "C" void kernel_launch(void* const* d_in, const int* in_sizes, int n_in,
                              void* d_out, int out_size, void* d_ws, size_t ws_size,
                              hipStream_t stream) {
    const float* m      = (const float*)d_in[0];
    const float* z      = (const float*)d_in[1];
    const float* mask   = (const float*)d_in[2];
    const float* ln_m_w = (const float*)d_in[3];
    const float* ln_m_b = (const float*)d_in[4];
    const float* ln_z_w = (const float*)d_in[5];
    const float* ln_z_b = (const float*)d_in[6];
    const float* Wz     = (const float*)d_in[7];
    const float* Wv     = (const float*)d_in[8];
    const float* Wg     = (const float*)d_in[9];
    const float* Wo     = (const float*)d_in[10];
    float* out = (float*)d_out;
    char* ws = (char*)d_ws;

    float* bias = (float*)(ws + OFF_BIAS);
    u16* Wt     = (u16*)(ws + OFF_WT);
    u16* Wot    = (u16*)(ws + OFF_WOT);
    u16* a      = (u16*)(ws + OFF_A);
    u16* vtw    = (u16*)(ws + OFF_VT);
    u16* gw     = (u16*)(ws + OFF_G);
    u16* ow     = (u16*)(ws + OFF_O);
    u16* mlnw   = (u16*)(ws + OFF_MLN);
    float* zbw  = (float*)(ws + OFF_ZB);
    u16* WWT    = (u16*)(ws + OFF_WWT);
    float* C1   = (float*)(ws + OFF_C1);
    float* C2   = (float*)(ws + OFF_C2);

    k_prep_all<<<6915, 256, 0, stream>>>(mask, Wz, ln_z_w, ln_z_b, Wv, Wg, Wo, m,
                                         ln_m_w, ln_m_b, bias, WWT, C1, C2, Wt, Wot, mlnw);
    k_zb<<<2304, 256, 0, stream>>>(z, WWT, C1, C2, zbw);
    k_soft<<<768, 256, 0, stream>>>(zbw, bias, a);
    k_gemm_vg<<<192 * 4, 256, 0, stream>>>(mlnw, Wt, vtw, gw);
    k_attn2<<<384, 256, 0, stream>>>(a, vtw, ow);
    k_gemm_out<<<192 * 2, 256, 0, stream>>>(ow, gw, Wot, out);
}

// Round 6
// 85.000 us; speedup vs baseline: 3.8825x; 1.0624x over previous
//
#include <hip/hip_runtime.h>
#include <math.h>

#define S 64
#define NRES 384
#define CM 256
#define CZ 128
#define NH 8
#define CH 32
#define HC 256

typedef unsigned short u16;
typedef __attribute__((ext_vector_type(8))) short bf16x8;
typedef __attribute__((ext_vector_type(4))) float f32x4;
typedef __attribute__((ext_vector_type(8))) unsigned short ushort8;
typedef __attribute__((ext_vector_type(4))) unsigned short ushort4_t;

// ---- workspace byte offsets ----
#define OFF_BIAS 0            // 384 f32
#define OFF_WT   200704       // 512*256 bf16 (Wv|Wg transposed)
#define OFF_WOT  462848       // 256*256 bf16 (Wo transposed)
#define OFF_A    593920       // 8*384*384 bf16
#define OFF_VT   2953216      // [h][s][c][n] 8*64*32*384 bf16
#define OFF_G    15536128     // 24576*256 bf16
#define OFF_O    28119040     // 24576*256 bf16
#define OFF_MLN  40701952     // 24576*256 bf16 (LN(m) pre-cast)
// overlapped (lifetimes disjoint in stream order):
#define OFF_ZB   OFF_O        // 147456*8 f32; dead before k_attn2 writes o

__device__ __forceinline__ u16 f2bf(float f) {
    union { float f; unsigned int u; } v; v.f = f;
    unsigned int u = v.u;
    u += 0x7fff + ((u >> 16) & 1);
    return (u16)(u >> 16);
}
__device__ __forceinline__ float bf2f(u16 b) {
    union { float f; unsigned int u; } v; v.u = ((unsigned int)b) << 16;
    return v.f;
}
// async global->LDS, 16B per lane, dest = wave-uniform base + lane*16
__device__ __forceinline__ void gload16(const u16* g, u16* l) {
    __builtin_amdgcn_global_load_lds(
        (const __attribute__((address_space(1))) void*)g,
        (__attribute__((address_space(3))) void*)l, 16, 0, 0);
}

// =====================  stage 1: zb | bias | Wt | Wot | mln  =================
// blocks: [0,2304) zb; [2304,2306) bias; [2306,2818) Wt; [2818,3074) Wot;
//         [3074,9218) m_ln
__global__ __launch_bounds__(256) void k_stage1(
        const float* __restrict__ z, const float* __restrict__ Wz,
        const float* __restrict__ lzw, const float* __restrict__ lzb,
        const float* __restrict__ mask,
        const float* __restrict__ Wv, const float* __restrict__ Wg,
        const float* __restrict__ Wo, const float* __restrict__ m,
        const float* __restrict__ lmw, const float* __restrict__ lmb,
        float* __restrict__ zb, float* __restrict__ bias,
        u16* __restrict__ Wt, u16* __restrict__ Wot, u16* __restrict__ mln) {
    const int bid = blockIdx.x, tid = threadIdx.x;
    if (bid < 2304) {
        // ---- zb logits via MFMA (self-sufficient: WW/C1/C2 inline) ----
        const int wave = tid >> 6, lane = tid & 63;
        const int rl = lane & 15, kg = lane >> 4;
        const int row0 = bid * 64 + wave * 16;
        const float* zrow = z + (size_t)(row0 + rl) * CZ + kg * 8;
        bf16x8 af[4];
        float sm = 0.f, sq = 0.f;
        #pragma unroll
        for (int t = 0; t < 4; ++t) {
            const float4 x0 = *(const float4*)&zrow[t * 32];
            const float4 x1 = *(const float4*)&zrow[t * 32 + 4];
            float xs[8] = {x0.x, x0.y, x0.z, x0.w, x1.x, x1.y, x1.z, x1.w};
            u16 tmp[8];
            #pragma unroll
            for (int e = 0; e < 8; ++e) {
                sm += xs[e]; sq += xs[e] * xs[e];
                tmp[e] = f2bf(xs[e]);
            }
            af[t] = *(bf16x8*)tmp;
        }
        sm += __shfl_xor(sm, 16); sq += __shfl_xor(sq, 16);
        sm += __shfl_xor(sm, 32); sq += __shfl_xor(sq, 32);
        const float mu = sm * (1.0f / CZ);
        const float var = sq * (1.0f / CZ) - mu * mu;
        const float rs = rsqrtf(var + 1e-5f);
        // C1/C2: all lanes, h=lane&7, 8 segments of 16 c, then tree-reduce
        const int hh = lane & 7, seg = lane >> 3;
        float s1 = 0.f, s2 = 0.f;
        #pragma unroll
        for (int ci = 0; ci < 16; ++ci) {
            const int c = seg * 16 + ci;
            const float wz = Wz[c * NH + hh];
            s1 += lzw[c] * wz;
            s2 += lzb[c] * wz;
        }
        #pragma unroll
        for (int off = 8; off < 64; off <<= 1) {
            s1 += __shfl_xor(s1, off);
            s2 += __shfl_xor(s2, off);
        }
        // B frags: WW^T[h=rl][c], zero for rl>=8
        bf16x8 bfr[4];
        #pragma unroll
        for (int t = 0; t < 4; ++t) {
            u16 tmp[8];
            #pragma unroll
            for (int e = 0; e < 8; ++e) {
                const int c = t * 32 + kg * 8 + e;
                tmp[e] = (rl < 8) ? f2bf(lzw[c] * Wz[c * NH + rl]) : (u16)0;
            }
            bfr[t] = *(bf16x8*)tmp;
        }
        f32x4 acc = {};
        #pragma unroll
        for (int t = 0; t < 4; ++t)
            acc = __builtin_amdgcn_mfma_f32_16x16x32_bf16(af[t], bfr[t], acc, 0, 0, 0);
        #pragma unroll
        for (int r = 0; r < 4; ++r) {
            const int rr = kg * 4 + r;
            const float mu_r = __shfl(mu, rr);
            const float rs_r = __shfl(rs, rr);
            const float p = rs_r * (acc[r] - mu_r * s1) + s2;
            if (rl < 8) zb[(size_t)(row0 + rr) * NH + rl] = p;
        }
    } else if (bid < 2306) {
        const int k = (bid - 2304) * 256 + tid;
        if (k < NRES) {
            float mx = -1e30f;
            for (int s = 0; s < S; ++s) mx = fmaxf(mx, mask[s * NRES + k]);
            bias[k] = 1e9f * (mx - 1.0f);
        }
    } else if (bid < 2818) {
        const int i = (bid - 2306) * 256 + tid;
        const int n = i >> 8, k = i & 255;
        const float v = (n < HC) ? Wv[(size_t)k * HC + n] : Wg[(size_t)k * HC + (n - HC)];
        Wt[i] = f2bf(v);
    } else if (bid < 3074) {
        const int i = (bid - 2818) * 256 + tid;
        const int n = i >> 8, k = i & 255;
        Wot[i] = f2bf(Wo[(size_t)k * CM + n]);
    } else {
        const int row = (bid - 3074) * 4 + (tid >> 6);
        const int lane = tid & 63;
        const float4 x = *(const float4*)&m[(size_t)row * CM + lane * 4];
        float sm = x.x + x.y + x.z + x.w;
        float sq = x.x*x.x + x.y*x.y + x.z*x.z + x.w*x.w;
        #pragma unroll
        for (int off = 32; off >= 1; off >>= 1) {
            sm += __shfl_xor(sm, off);
            sq += __shfl_xor(sq, off);
        }
        const float mu = sm * (1.0f / CM);
        const float var = sq * (1.0f / CM) - mu * mu;
        const float rs = rsqrtf(var + 1e-5f);
        const float4 w4 = *(const float4*)&lmw[lane * 4];
        const float4 b4 = *(const float4*)&lmb[lane * 4];
        u16 t4[4];
        t4[0] = f2bf((x.x - mu) * rs * w4.x + b4.x);
        t4[1] = f2bf((x.y - mu) * rs * w4.y + b4.y);
        t4[2] = f2bf((x.z - mu) * rs * w4.z + b4.z);
        t4[3] = f2bf((x.w - mu) * rs * w4.w + b4.w);
        *(ushort4_t*)&mln[(size_t)row * CM + lane * 4] = *(ushort4_t*)t4;
    }
}

// =====================  stage 2: gemm_vg | soft  =============================
// blocks: [0,768) gemm_vg (XCD-swizzled); [768,1536) softmax
__global__ __launch_bounds__(256) void k_stage2(
        const u16* __restrict__ mln, const u16* __restrict__ Wt,
        const float* __restrict__ zb, const float* __restrict__ bias,
        u16* __restrict__ vt, u16* __restrict__ g_, u16* __restrict__ a_out) {
    __shared__ u16 As[128][32];
    __shared__ u16 Bs[128][32];
    const int bid = blockIdx.x, tid = threadIdx.x;
    if (bid >= 768) {
        // ---- softmax over k ----
        const int w = (bid - 768) * 4 + (tid >> 6);
        const int lane = tid & 63;
        const int h = w & 7, q = w >> 3;
        float v[6];
        float mx = -1e30f;
        #pragma unroll
        for (int t = 0; t < 6; ++t) {
            const int k = lane + 64 * t;
            v[t] = zb[((size_t)q * NRES + k) * NH + h] + bias[k];
            mx = fmaxf(mx, v[t]);
        }
        #pragma unroll
        for (int off = 32; off >= 1; off >>= 1) mx = fmaxf(mx, __shfl_xor(mx, off));
        float sum = 0.f;
        #pragma unroll
        for (int t = 0; t < 6; ++t) { v[t] = expf(v[t] - mx); sum += v[t]; }
        #pragma unroll
        for (int off = 32; off >= 1; off >>= 1) sum += __shfl_xor(sum, off);
        const float inv = 1.0f / sum;
        #pragma unroll
        for (int t = 0; t < 6; ++t)
            a_out[((size_t)h * NRES + q) * NRES + lane + 64 * t] = f2bf(v[t] * inv);
        return;
    }
    // ---- MFMA GEMM: m_ln @ [Wv|Wg] -> vt + g, gload_lds staging ----
    const int xcd = bid & 7, idx = bid >> 3;
    const int nt = idx & 3, mt = xcd * 24 + (idx >> 2);
    const int m0 = mt * 128, n0 = nt * 128;
    const int wave = tid >> 6, lane = tid & 63;
    const int wm = (wave >> 1) * 64, wn = (wave & 1) * 64;
    const int rl = lane & 15, kg = lane >> 4;
    const int lr = lane >> 2, lk = (lane & 3) * 8;
    const int wr = wave * 32;
    const u16* ag  = mln + (size_t)(m0 + wr + lr) * CM + lk;
    const u16* ag2 = ag + 16 * CM;
    const u16* bg  = Wt + (size_t)(n0 + wr + lr) * CM + lk;
    const u16* bg2 = bg + 16 * CM;
    u16* al  = &As[wr][0];
    u16* al2 = &As[wr + 16][0];
    u16* bl  = &Bs[wr][0];
    u16* bl2 = &Bs[wr + 16][0];
    const bool vhalf = (n0 < HC);
    f32x4 acc[4][4] = {};
    for (int kt = 0; kt < CM; kt += 32) {
        if (kt) __syncthreads();
        gload16(ag + kt, al);  gload16(ag2 + kt, al2);
        gload16(bg + kt, bl);  gload16(bg2 + kt, bl2);
        __syncthreads();
        bf16x8 af[4], bfr[4];
        #pragma unroll
        for (int i = 0; i < 4; ++i) af[i]  = *(const bf16x8*)&As[wm + i*16 + rl][kg*8];
        #pragma unroll
        for (int j = 0; j < 4; ++j) bfr[j] = *(const bf16x8*)&Bs[wn + j*16 + rl][kg*8];
        if (vhalf) {
            #pragma unroll
            for (int j = 0; j < 4; ++j)
                #pragma unroll
                for (int i = 0; i < 4; ++i)
                    acc[j][i] = __builtin_amdgcn_mfma_f32_16x16x32_bf16(bfr[j], af[i], acc[j][i], 0, 0, 0);
        } else {
            #pragma unroll
            for (int i = 0; i < 4; ++i)
                #pragma unroll
                for (int j = 0; j < 4; ++j)
                    acc[i][j] = __builtin_amdgcn_mfma_f32_16x16x32_bf16(af[i], bfr[j], acc[i][j], 0, 0, 0);
        }
    }
    if (vhalf) {
        #pragma unroll
        for (int j = 0; j < 4; ++j)
            #pragma unroll
            for (int r = 0; r < 4; ++r) {
                const int vcol = n0 + wn + j*16 + kg*4 + r;
                const int h = vcol >> 5, c = vcol & 31;
                #pragma unroll
                for (int i = 0; i < 4; ++i) {
                    const int mrowb = m0 + wm + i*16;
                    const int s = mrowb / NRES;
                    const int nn = mrowb - s * NRES + rl;
                    vt[(((size_t)h * S + s) * CH + c) * NRES + nn] = f2bf(acc[j][i][r]);
                }
            }
    } else {
        #pragma unroll
        for (int i = 0; i < 4; ++i)
            #pragma unroll
            for (int r = 0; r < 4; ++r) {
                const int row = m0 + wm + i*16 + kg*4 + r;
                #pragma unroll
                for (int j = 0; j < 4; ++j) {
                    const int gc = n0 + wn + j*16 + rl - HC;
                    g_[(size_t)row * HC + gc] = f2bf(1.0f / (1.0f + expf(-acc[i][j][r])));
                }
            }
    }
}

// ========== attn as per-h GEMM (one head per XCD), gload_lds staging =========
__global__ __launch_bounds__(256) void k_attn2(const u16* __restrict__ a_,
        const u16* __restrict__ vt, u16* __restrict__ o_) {
    __shared__ u16 As[128][32];
    __shared__ u16 Bs[128][32];
    const int tid = threadIdx.x;
    const int h = blockIdx.x & 7, rem = blockIdx.x >> 3;
    const int mt = rem >> 4, nt = rem & 15;
    const int q0 = mt * 128, sc0 = nt * 128;
    const int wave = tid >> 6, lane = tid & 63;
    const int wm = (wave >> 1) * 64, wn = (wave & 1) * 64;
    const int rl = lane & 15, kg = lane >> 4;
    const int lr = lane >> 2, lk = (lane & 3) * 8;
    const int wr = wave * 32;
    const u16* ag  = a_ + (size_t)h * NRES * NRES + (size_t)(q0 + wr + lr) * NRES + lk;
    const u16* ag2 = ag + 16 * NRES;
    const u16* bg  = vt + (size_t)h * S * CH * NRES + (size_t)(sc0 + wr + lr) * NRES + lk;
    const u16* bg2 = bg + 16 * NRES;
    u16* al  = &As[wr][0];
    u16* al2 = &As[wr + 16][0];
    u16* bl  = &Bs[wr][0];
    u16* bl2 = &Bs[wr + 16][0];
    f32x4 acc[4][4] = {};
    for (int kt = 0; kt < NRES; kt += 32) {
        if (kt) __syncthreads();
        gload16(ag + kt, al);  gload16(ag2 + kt, al2);
        gload16(bg + kt, bl);  gload16(bg2 + kt, bl2);
        __syncthreads();
        bf16x8 af[4], bfr[4];
        #pragma unroll
        for (int i = 0; i < 4; ++i) af[i]  = *(const bf16x8*)&As[wm + i*16 + rl][kg*8];
        #pragma unroll
        for (int j = 0; j < 4; ++j) bfr[j] = *(const bf16x8*)&Bs[wn + j*16 + rl][kg*8];
        #pragma unroll
        for (int i = 0; i < 4; ++i)
            #pragma unroll
            for (int j = 0; j < 4; ++j)
                acc[i][j] = __builtin_amdgcn_mfma_f32_16x16x32_bf16(af[i], bfr[j], acc[i][j], 0, 0, 0);
    }
    #pragma unroll
    for (int i = 0; i < 4; ++i)
        #pragma unroll
        for (int r = 0; r < 4; ++r) {
            const int q = q0 + wm + i*16 + kg*4 + r;
            #pragma unroll
            for (int j = 0; j < 4; ++j) {
                const int sc = sc0 + wn + j*16 + rl;
                const int s = sc >> 5, c = sc & 31;
                o_[(((size_t)s * NRES + q) * NH + h) * CH + c] = f2bf(acc[i][j][r]);
            }
        }
}

// ========== out = (o*g) @ Wo  (XCD-swizzled, B via gload_lds) ================
__global__ __launch_bounds__(256) void k_gemm_out(const u16* __restrict__ o_,
        const u16* __restrict__ g_, const u16* __restrict__ Wot,
        float* __restrict__ out) {
    __shared__ u16 As[128][40];
    __shared__ u16 Bs[128][32];
    const int tid = threadIdx.x;
    const int xcd = blockIdx.x & 7, idx = blockIdx.x >> 3;
    const int nt = idx & 1, mt = xcd * 24 + (idx >> 1);
    const int m0 = mt * 128, n0 = nt * 128;
    const int wave = tid >> 6, lane = tid & 63;
    const int wm = (wave >> 1) * 64, wn = (wave & 1) * 64;
    const int rl = lane & 15, kg = lane >> 4;
    const int lr = lane >> 2, lk = (lane & 3) * 8;
    const int wr = wave * 32;
    const int sr = tid >> 1, sh = (tid & 1) * 16;
    const u16* orow = o_ + (size_t)(m0 + sr) * HC;
    const u16* grow = g_ + (size_t)(m0 + sr) * HC;
    const u16* bg  = Wot + (size_t)(n0 + wr + lr) * HC + lk;
    const u16* bg2 = bg + 16 * HC;
    u16* bl  = &Bs[wr][0];
    u16* bl2 = &Bs[wr + 16][0];
    f32x4 acc[4][4] = {};
    for (int kt = 0; kt < HC; kt += 32) {
        if (kt) __syncthreads();
        gload16(bg + kt, bl);  gload16(bg2 + kt, bl2);
        {
            u16 tmp[16];
            const ushort8 ov0 = *(const ushort8*)&orow[kt + sh];
            const ushort8 ov1 = *(const ushort8*)&orow[kt + sh + 8];
            const ushort8 gv0 = *(const ushort8*)&grow[kt + sh];
            const ushort8 gv1 = *(const ushort8*)&grow[kt + sh + 8];
            #pragma unroll
            for (int p = 0; p < 8; ++p) {
                tmp[p]     = f2bf(bf2f(ov0[p]) * bf2f(gv0[p]));
                tmp[p + 8] = f2bf(bf2f(ov1[p]) * bf2f(gv1[p]));
            }
            *(ushort8*)&As[sr][sh]     = *(ushort8*)&tmp[0];
            *(ushort8*)&As[sr][sh + 8] = *(ushort8*)&tmp[8];
        }
        __syncthreads();
        bf16x8 af[4], bfr[4];
        #pragma unroll
        for (int i = 0; i < 4; ++i) af[i]  = *(const bf16x8*)&As[wm + i*16 + rl][kg*8];
        #pragma unroll
        for (int j = 0; j < 4; ++j) bfr[j] = *(const bf16x8*)&Bs[wn + j*16 + rl][kg*8];
        #pragma unroll
        for (int i = 0; i < 4; ++i)
            #pragma unroll
            for (int j = 0; j < 4; ++j)
                acc[i][j] = __builtin_amdgcn_mfma_f32_16x16x32_bf16(af[i], bfr[j], acc[i][j], 0, 0, 0);
    }
    #pragma unroll
    for (int i = 0; i < 4; ++i)
        #pragma unroll
        for (int r = 0; r < 4; ++r) {
            const int row = m0 + wm + i*16 + kg*4 + r;
            #pragma unroll
            for (int j = 0; j < 4; ++j)
                out[(size_t)row * CM + n0 + wn + j*16 + rl] = acc[i][j][r];
        }
}

extern "C" void kernel_launch(void* const* d_in, const int* in_sizes, int n_in,
                              void* d_out, int out_size, void* d_ws, size_t ws_size,
                              hipStream_t stream) {
    const float* m      = (const float*)d_in[0];
    const float* z      = (const float*)d_in[1];
    const float* mask   = (const float*)d_in[2];
    const float* ln_m_w = (const float*)d_in[3];
    const float* ln_m_b = (const float*)d_in[4];
    const float* ln_z_w = (const float*)d_in[5];
    const float* ln_z_b = (const float*)d_in[6];
    const float* Wz     = (const float*)d_in[7];
    const float* Wv     = (const float*)d_in[8];
    const float* Wg     = (const float*)d_in[9];
    const float* Wo     = (const float*)d_in[10];
    float* out = (float*)d_out;
    char* ws = (char*)d_ws;

    float* bias = (float*)(ws + OFF_BIAS);
    u16* Wt     = (u16*)(ws + OFF_WT);
    u16* Wot    = (u16*)(ws + OFF_WOT);
    u16* a      = (u16*)(ws + OFF_A);
    u16* vtw    = (u16*)(ws + OFF_VT);
    u16* gw     = (u16*)(ws + OFF_G);
    u16* ow     = (u16*)(ws + OFF_O);
    u16* mlnw   = (u16*)(ws + OFF_MLN);
    float* zbw  = (float*)(ws + OFF_ZB);

    k_stage1<<<9218, 256, 0, stream>>>(z, Wz, ln_z_w, ln_z_b, mask, Wv, Wg, Wo,
                                       m, ln_m_w, ln_m_b, zbw, bias, Wt, Wot, mlnw);
    k_stage2<<<1536, 256, 0, stream>>>(mlnw, Wt, zbw, bias, vtw, gw, a);
    k_attn2<<<384, 256, 0, stream>>>(a, vtw, ow);
    k_gemm_out<<<384, 256, 0, stream>>>(ow, gw, Wot, out);
}

// Round 7
// 76.773 us; speedup vs baseline: 4.2985x; 1.1072x over previous
//
#include <hip/hip_runtime.h>
#include <math.h>

#define S 64
#define NRES 384
#define CM 256
#define CZ 128
#define NH 8
#define CH 32
#define HC 256
#define NROW 147456   // NRES*NRES

typedef unsigned short u16;
typedef __attribute__((ext_vector_type(8))) short bf16x8;
typedef __attribute__((ext_vector_type(4))) float f32x4;
typedef __attribute__((ext_vector_type(8))) unsigned short ushort8;
typedef __attribute__((ext_vector_type(4))) unsigned short ushort4_t;

// ---- workspace byte offsets ----
#define OFF_BIAS 0            // 384 f32
#define OFF_WT   200704       // 512*256 bf16 (Wv|Wg transposed)
#define OFF_WOT  462848       // 256*256 bf16 (Wo transposed)
#define OFF_A    593920       // 8*384*384 bf16
#define OFF_VT   2953216      // [h][s][c][n] 8*64*32*384 bf16
#define OFF_G    15536128     // 24576*256 bf16
#define OFF_O    28119040     // 24576*256 bf16
#define OFF_MLN  40701952     // 24576*256 bf16 (LN(m) pre-cast)
// overlapped (lifetimes disjoint in stream order):
#define OFF_ZB   OFF_O        // [8][147456] f32 = 4.72MB; dead before k_attn2 writes o

__device__ __forceinline__ u16 f2bf(float f) {
    union { float f; unsigned int u; } v; v.f = f;
    unsigned int u = v.u;
    u += 0x7fff + ((u >> 16) & 1);
    return (u16)(u >> 16);
}
__device__ __forceinline__ float bf2f(u16 b) {
    union { float f; unsigned int u; } v; v.u = ((unsigned int)b) << 16;
    return v.f;
}
// async global->LDS, 16B per lane, dest = wave-uniform base + lane*16
__device__ __forceinline__ void gload16(const u16* g, u16* l) {
    __builtin_amdgcn_global_load_lds(
        (const __attribute__((address_space(1))) void*)g,
        (__attribute__((address_space(3))) void*)l, 16, 0, 0);
}

// =====================  stage 1: zb | bias | Wt | Wot | mln  =================
// blocks: [0,1152) zb (128 rows each); [1152,1154) bias; [1154,1666) Wt;
//         [1666,1922) Wot; [1922,8066) m_ln
__global__ __launch_bounds__(256) void k_stage1(
        const float* __restrict__ z, const float* __restrict__ Wz,
        const float* __restrict__ lzw, const float* __restrict__ lzb,
        const float* __restrict__ mask,
        const float* __restrict__ Wv, const float* __restrict__ Wg,
        const float* __restrict__ Wo, const float* __restrict__ m,
        const float* __restrict__ lmw, const float* __restrict__ lmb,
        float* __restrict__ zb, float* __restrict__ bias,
        u16* __restrict__ Wt, u16* __restrict__ Wot, u16* __restrict__ mln) {
    const int bid = blockIdx.x, tid = threadIdx.x;
    if (bid < 1152) {
        // ---- zb logits via MFMA; WWT/C1/C2 staged in LDS once per block ----
        __shared__ u16 sWWT[16 * 128];
        __shared__ float sPart[2][2][8];
        const int wave = tid >> 6, lane = tid & 63;
        const int rl = lane & 15, kg = lane >> 4;
        if (tid < 128) {
            const int c = tid;
            const float4 wz0 = *(const float4*)&Wz[c * 8];
            const float4 wz1 = *(const float4*)&Wz[c * 8 + 4];
            const float lw = lzw[c], lbv = lzb[c];
            float wzv[8] = {wz0.x, wz0.y, wz0.z, wz0.w, wz1.x, wz1.y, wz1.z, wz1.w};
            float ww[8], wb[8];
            #pragma unroll
            for (int h = 0; h < 8; ++h) {
                ww[h] = lw * wzv[h];
                wb[h] = lbv * wzv[h];
                sWWT[h * 128 + c] = f2bf(ww[h]);
                sWWT[(8 + h) * 128 + c] = 0;
            }
            #pragma unroll
            for (int h = 0; h < 8; ++h) {
                #pragma unroll
                for (int off = 1; off < 64; off <<= 1) {
                    ww[h] += __shfl_xor(ww[h], off);
                    wb[h] += __shfl_xor(wb[h], off);
                }
            }
            if (lane == 0) {
                #pragma unroll
                for (int h = 0; h < 8; ++h) {
                    sPart[wave][0][h] = ww[h];
                    sPart[wave][1][h] = wb[h];
                }
            }
        }
        __syncthreads();
        const float c1 = (rl < 8) ? (sPart[0][0][rl] + sPart[1][0][rl]) : 0.f;
        const float c2 = (rl < 8) ? (sPart[0][1][rl] + sPart[1][1][rl]) : 0.f;
        bf16x8 bfr[4];
        #pragma unroll
        for (int t = 0; t < 4; ++t)
            bfr[t] = *(const bf16x8*)&sWWT[rl * 128 + kg * 8 + t * 32];
        #pragma unroll
        for (int it = 0; it < 2; ++it) {
            const int row0 = bid * 128 + it * 64 + wave * 16;
            const float* zrow = z + (size_t)(row0 + rl) * CZ + kg * 8;
            bf16x8 af[4];
            float sm = 0.f, sq = 0.f;
            #pragma unroll
            for (int t = 0; t < 4; ++t) {
                const float4 x0 = *(const float4*)&zrow[t * 32];
                const float4 x1 = *(const float4*)&zrow[t * 32 + 4];
                float xs[8] = {x0.x, x0.y, x0.z, x0.w, x1.x, x1.y, x1.z, x1.w};
                u16 tmp[8];
                #pragma unroll
                for (int e = 0; e < 8; ++e) {
                    sm += xs[e]; sq += xs[e] * xs[e];
                    tmp[e] = f2bf(xs[e]);
                }
                af[t] = *(bf16x8*)tmp;
            }
            sm += __shfl_xor(sm, 16); sq += __shfl_xor(sq, 16);
            sm += __shfl_xor(sm, 32); sq += __shfl_xor(sq, 32);
            const float mu = sm * (1.0f / CZ);
            const float var = sq * (1.0f / CZ) - mu * mu;
            const float rs = rsqrtf(var + 1e-5f);
            f32x4 acc = {};
            #pragma unroll
            for (int t = 0; t < 4; ++t)
                acc = __builtin_amdgcn_mfma_f32_16x16x32_bf16(af[t], bfr[t], acc, 0, 0, 0);
            f32x4 pv;
            #pragma unroll
            for (int r = 0; r < 4; ++r) {
                const int rr = kg * 4 + r;
                const float mu_r = __shfl(mu, rr);
                const float rs_r = __shfl(rs, rr);
                pv[r] = rs_r * (acc[r] - mu_r * c1) + c2;
            }
            if (rl < 8)
                *(f32x4*)&zb[(size_t)rl * NROW + row0 + kg * 4] = pv;
        }
    } else if (bid < 1154) {
        const int k = (bid - 1152) * 256 + tid;
        if (k < NRES) {
            float mx = -1e30f;
            for (int s = 0; s < S; ++s) mx = fmaxf(mx, mask[s * NRES + k]);
            bias[k] = 1e9f * (mx - 1.0f);
        }
    } else if (bid < 1666) {
        const int i = (bid - 1154) * 256 + tid;
        const int n = i >> 8, k = i & 255;
        const float v = (n < HC) ? Wv[(size_t)k * HC + n] : Wg[(size_t)k * HC + (n - HC)];
        Wt[i] = f2bf(v);
    } else if (bid < 1922) {
        const int i = (bid - 1666) * 256 + tid;
        const int n = i >> 8, k = i & 255;
        Wot[i] = f2bf(Wo[(size_t)k * CM + n]);
    } else {
        const int row = (bid - 1922) * 4 + (tid >> 6);
        const int lane = tid & 63;
        const float4 x = *(const float4*)&m[(size_t)row * CM + lane * 4];
        float sm = x.x + x.y + x.z + x.w;
        float sq = x.x*x.x + x.y*x.y + x.z*x.z + x.w*x.w;
        #pragma unroll
        for (int off = 32; off >= 1; off >>= 1) {
            sm += __shfl_xor(sm, off);
            sq += __shfl_xor(sq, off);
        }
        const float mu = sm * (1.0f / CM);
        const float var = sq * (1.0f / CM) - mu * mu;
        const float rs = rsqrtf(var + 1e-5f);
        const float4 w4 = *(const float4*)&lmw[lane * 4];
        const float4 b4 = *(const float4*)&lmb[lane * 4];
        u16 t4[4];
        t4[0] = f2bf((x.x - mu) * rs * w4.x + b4.x);
        t4[1] = f2bf((x.y - mu) * rs * w4.y + b4.y);
        t4[2] = f2bf((x.z - mu) * rs * w4.z + b4.z);
        t4[3] = f2bf((x.w - mu) * rs * w4.w + b4.w);
        *(ushort4_t*)&mln[(size_t)row * CM + lane * 4] = *(ushort4_t*)t4;
    }
}

// =====================  stage 2: gemm_vg | soft  =============================
// blocks: [0,768) gemm_vg (XCD-swizzled); [768,1536) softmax
__global__ __launch_bounds__(256) void k_stage2(
        const u16* __restrict__ mln, const u16* __restrict__ Wt,
        const float* __restrict__ zb, const float* __restrict__ bias,
        u16* __restrict__ vt, u16* __restrict__ g_, u16* __restrict__ a_out) {
    __shared__ u16 As[128][32];
    __shared__ u16 Bs[128][32];
    const int bid = blockIdx.x, tid = threadIdx.x;
    if (bid >= 768) {
        // ---- softmax over k (coalesced zb[h][q*384+k] reads) ----
        const int w = (bid - 768) * 4 + (tid >> 6);
        const int lane = tid & 63;
        const int h = w & 7, q = w >> 3;
        const float* zbh = zb + (size_t)h * NROW + (size_t)q * NRES;
        float v[6];
        float mx = -1e30f;
        #pragma unroll
        for (int t = 0; t < 6; ++t) {
            const int k = lane + 64 * t;
            v[t] = zbh[k] + bias[k];
            mx = fmaxf(mx, v[t]);
        }
        #pragma unroll
        for (int off = 32; off >= 1; off >>= 1) mx = fmaxf(mx, __shfl_xor(mx, off));
        float sum = 0.f;
        #pragma unroll
        for (int t = 0; t < 6; ++t) { v[t] = expf(v[t] - mx); sum += v[t]; }
        #pragma unroll
        for (int off = 32; off >= 1; off >>= 1) sum += __shfl_xor(sum, off);
        const float inv = 1.0f / sum;
        #pragma unroll
        for (int t = 0; t < 6; ++t)
            a_out[((size_t)h * NRES + q) * NRES + lane + 64 * t] = f2bf(v[t] * inv);
        return;
    }
    // ---- MFMA GEMM: m_ln @ [Wv|Wg] -> vt + g, gload_lds staging ----
    const int xcd = bid & 7, idx = bid >> 3;
    const int nt = idx & 3, mt = xcd * 24 + (idx >> 2);
    const int m0 = mt * 128, n0 = nt * 128;
    const int wave = tid >> 6, lane = tid & 63;
    const int wm = (wave >> 1) * 64, wn = (wave & 1) * 64;
    const int rl = lane & 15, kg = lane >> 4;
    const int lr = lane >> 2, lk = (lane & 3) * 8;
    const int wr = wave * 32;
    const u16* ag  = mln + (size_t)(m0 + wr + lr) * CM + lk;
    const u16* ag2 = ag + 16 * CM;
    const u16* bg  = Wt + (size_t)(n0 + wr + lr) * CM + lk;
    const u16* bg2 = bg + 16 * CM;
    u16* al  = &As[wr][0];
    u16* al2 = &As[wr + 16][0];
    u16* bl  = &Bs[wr][0];
    u16* bl2 = &Bs[wr + 16][0];
    const bool vhalf = (n0 < HC);
    f32x4 acc[4][4] = {};
    for (int kt = 0; kt < CM; kt += 32) {
        if (kt) __syncthreads();
        gload16(ag + kt, al);  gload16(ag2 + kt, al2);
        gload16(bg + kt, bl);  gload16(bg2 + kt, bl2);
        __syncthreads();
        bf16x8 af[4], bfr[4];
        #pragma unroll
        for (int i = 0; i < 4; ++i) af[i]  = *(const bf16x8*)&As[wm + i*16 + rl][kg*8];
        #pragma unroll
        for (int j = 0; j < 4; ++j) bfr[j] = *(const bf16x8*)&Bs[wn + j*16 + rl][kg*8];
        if (vhalf) {
            #pragma unroll
            for (int j = 0; j < 4; ++j)
                #pragma unroll
                for (int i = 0; i < 4; ++i)
                    acc[j][i] = __builtin_amdgcn_mfma_f32_16x16x32_bf16(bfr[j], af[i], acc[j][i], 0, 0, 0);
        } else {
            #pragma unroll
            for (int i = 0; i < 4; ++i)
                #pragma unroll
                for (int j = 0; j < 4; ++j)
                    acc[i][j] = __builtin_amdgcn_mfma_f32_16x16x32_bf16(af[i], bfr[j], acc[i][j], 0, 0, 0);
        }
    }
    if (vhalf) {
        #pragma unroll
        for (int j = 0; j < 4; ++j)
            #pragma unroll
            for (int r = 0; r < 4; ++r) {
                const int vcol = n0 + wn + j*16 + kg*4 + r;
                const int h = vcol >> 5, c = vcol & 31;
                #pragma unroll
                for (int i = 0; i < 4; ++i) {
                    const int mrowb = m0 + wm + i*16;
                    const int s = mrowb / NRES;
                    const int nn = mrowb - s * NRES + rl;
                    vt[(((size_t)h * S + s) * CH + c) * NRES + nn] = f2bf(acc[j][i][r]);
                }
            }
    } else {
        #pragma unroll
        for (int i = 0; i < 4; ++i)
            #pragma unroll
            for (int r = 0; r < 4; ++r) {
                const int row = m0 + wm + i*16 + kg*4 + r;
                #pragma unroll
                for (int j = 0; j < 4; ++j) {
                    const int gc = n0 + wn + j*16 + rl - HC;
                    g_[(size_t)row * HC + gc] = f2bf(1.0f / (1.0f + expf(-acc[i][j][r])));
                }
            }
    }
}

// ========== attn as per-h GEMM (one head per XCD), gload_lds staging =========
__global__ __launch_bounds__(256) void k_attn2(const u16* __restrict__ a_,
        const u16* __restrict__ vt, u16* __restrict__ o_) {
    __shared__ u16 As[128][32];
    __shared__ u16 Bs[128][32];
    const int tid = threadIdx.x;
    const int h = blockIdx.x & 7, rem = blockIdx.x >> 3;
    const int mt = rem >> 4, nt = rem & 15;
    const int q0 = mt * 128, sc0 = nt * 128;
    const int wave = tid >> 6, lane = tid & 63;
    const int wm = (wave >> 1) * 64, wn = (wave & 1) * 64;
    const int rl = lane & 15, kg = lane >> 4;
    const int lr = lane >> 2, lk = (lane & 3) * 8;
    const int wr = wave * 32;
    const u16* ag  = a_ + (size_t)h * NRES * NRES + (size_t)(q0 + wr + lr) * NRES + lk;
    const u16* ag2 = ag + 16 * NRES;
    const u16* bg  = vt + (size_t)h * S * CH * NRES + (size_t)(sc0 + wr + lr) * NRES + lk;
    const u16* bg2 = bg + 16 * NRES;
    u16* al  = &As[wr][0];
    u16* al2 = &As[wr + 16][0];
    u16* bl  = &Bs[wr][0];
    u16* bl2 = &Bs[wr + 16][0];
    f32x4 acc[4][4] = {};
    for (int kt = 0; kt < NRES; kt += 32) {
        if (kt) __syncthreads();
        gload16(ag + kt, al);  gload16(ag2 + kt, al2);
        gload16(bg + kt, bl);  gload16(bg2 + kt, bl2);
        __syncthreads();
        bf16x8 af[4], bfr[4];
        #pragma unroll
        for (int i = 0; i < 4; ++i) af[i]  = *(const bf16x8*)&As[wm + i*16 + rl][kg*8];
        #pragma unroll
        for (int j = 0; j < 4; ++j) bfr[j] = *(const bf16x8*)&Bs[wn + j*16 + rl][kg*8];
        #pragma unroll
        for (int i = 0; i < 4; ++i)
            #pragma unroll
            for (int j = 0; j < 4; ++j)
                acc[i][j] = __builtin_amdgcn_mfma_f32_16x16x32_bf16(af[i], bfr[j], acc[i][j], 0, 0, 0);
    }
    #pragma unroll
    for (int i = 0; i < 4; ++i)
        #pragma unroll
        for (int r = 0; r < 4; ++r) {
            const int q = q0 + wm + i*16 + kg*4 + r;
            #pragma unroll
            for (int j = 0; j < 4; ++j) {
                const int sc = sc0 + wn + j*16 + rl;
                const int s = sc >> 5, c = sc & 31;
                o_[(((size_t)s * NRES + q) * NH + h) * CH + c] = f2bf(acc[i][j][r]);
            }
        }
}

// ========== out = (o*g) @ Wo  (XCD-swizzled, B via gload_lds) ================
__global__ __launch_bounds__(256) void k_gemm_out(const u16* __restrict__ o_,
        const u16* __restrict__ g_, const u16* __restrict__ Wot,
        float* __restrict__ out) {
    __shared__ u16 As[128][40];
    __shared__ u16 Bs[128][32];
    const int tid = threadIdx.x;
    const int xcd = blockIdx.x & 7, idx = blockIdx.x >> 3;
    const int nt = idx & 1, mt = xcd * 24 + (idx >> 1);
    const int m0 = mt * 128, n0 = nt * 128;
    const int wave = tid >> 6, lane = tid & 63;
    const int wm = (wave >> 1) * 64, wn = (wave & 1) * 64;
    const int rl = lane & 15, kg = lane >> 4;
    const int lr = lane >> 2, lk = (lane & 3) * 8;
    const int wr = wave * 32;
    const int sr = tid >> 1, sh = (tid & 1) * 16;
    const u16* orow = o_ + (size_t)(m0 + sr) * HC;
    const u16* grow = g_ + (size_t)(m0 + sr) * HC;
    const u16* bg  = Wot + (size_t)(n0 + wr + lr) * HC + lk;
    const u16* bg2 = bg + 16 * HC;
    u16* bl  = &Bs[wr][0];
    u16* bl2 = &Bs[wr + 16][0];
    f32x4 acc[4][4] = {};
    for (int kt = 0; kt < HC; kt += 32) {
        if (kt) __syncthreads();
        gload16(bg + kt, bl);  gload16(bg2 + kt, bl2);
        {
            u16 tmp[16];
            const ushort8 ov0 = *(const ushort8*)&orow[kt + sh];
            const ushort8 ov1 = *(const ushort8*)&orow[kt + sh + 8];
            const ushort8 gv0 = *(const ushort8*)&grow[kt + sh];
            const ushort8 gv1 = *(const ushort8*)&grow[kt + sh + 8];
            #pragma unroll
            for (int p = 0; p < 8; ++p) {
                tmp[p]     = f2bf(bf2f(ov0[p]) * bf2f(gv0[p]));
                tmp[p + 8] = f2bf(bf2f(ov1[p]) * bf2f(gv1[p]));
            }
            *(ushort8*)&As[sr][sh]     = *(ushort8*)&tmp[0];
            *(ushort8*)&As[sr][sh + 8] = *(ushort8*)&tmp[8];
        }
        __syncthreads();
        bf16x8 af[4], bfr[4];
        #pragma unroll
        for (int i = 0; i < 4; ++i) af[i]  = *(const bf16x8*)&As[wm + i*16 + rl][kg*8];
        #pragma unroll
        for (int j = 0; j < 4; ++j) bfr[j] = *(const bf16x8*)&Bs[wn + j*16 + rl][kg*8];
        #pragma unroll
        for (int i = 0; i < 4; ++i)
            #pragma unroll
            for (int j = 0; j < 4; ++j)
                acc[i][j] = __builtin_amdgcn_mfma_f32_16x16x32_bf16(af[i], bfr[j], acc[i][j], 0, 0, 0);
    }
    #pragma unroll
    for (int i = 0; i < 4; ++i)
        #pragma unroll
        for (int r = 0; r < 4; ++r) {
            const int row = m0 + wm + i*16 + kg*4 + r;
            #pragma unroll
            for (int j = 0; j < 4; ++j)
                out[(size_t)row * CM + n0 + wn + j*16 + rl] = acc[i][j][r];
        }
}

extern "C" void kernel_launch(void* const* d_in, const int* in_sizes, int n_in,
                              void* d_out, int out_size, void* d_ws, size_t ws_size,
                              hipStream_t stream) {
    const float* m      = (const float*)d_in[0];
    const float* z      = (const float*)d_in[1];
    const float* mask   = (const float*)d_in[2];
    const float* ln_m_w = (const float*)d_in[3];
    const float* ln_m_b = (const float*)d_in[4];
    const float* ln_z_w = (const float*)d_in[5];
    const float* ln_z_b = (const float*)d_in[6];
    const float* Wz     = (const float*)d_in[7];
    const float* Wv     = (const float*)d_in[8];
    const float* Wg     = (const float*)d_in[9];
    const float* Wo     = (const float*)d_in[10];
    float* out = (float*)d_out;
    char* ws = (char*)d_ws;

    float* bias = (float*)(ws + OFF_BIAS);
    u16* Wt     = (u16*)(ws + OFF_WT);
    u16* Wot    = (u16*)(ws + OFF_WOT);
    u16* a      = (u16*)(ws + OFF_A);
    u16* vtw    = (u16*)(ws + OFF_VT);
    u16* gw     = (u16*)(ws + OFF_G);
    u16* ow     = (u16*)(ws + OFF_O);
    u16* mlnw   = (u16*)(ws + OFF_MLN);
    float* zbw  = (float*)(ws + OFF_ZB);

    k_stage1<<<8066, 256, 0, stream>>>(z, Wz, ln_z_w, ln_z_b, mask, Wv, Wg, Wo,
                                       m, ln_m_w, ln_m_b, zbw, bias, Wt, Wot, mlnw);
    k_stage2<<<1536, 256, 0, stream>>>(mlnw, Wt, zbw, bias, vtw, gw, a);
    k_attn2<<<384, 256, 0, stream>>>(a, vtw, ow);
    k_gemm_out<<<384, 256, 0, stream>>>(ow, gw, Wot, out);
}